// Round 1
// baseline (4499.051 us; speedup 1.0000x reference)
//
#include <hip/hip_runtime.h>
#include <hip/hip_bf16.h>
#include <math.h>

// Problem constants
#define BB 2
#define TT 2048
#define DD 1024
#define RR 64
#define RS 16
#define MT (BB*TT)   // 4096 flattened rows

// ---------------------------------------------------------------------------
// Generic tiled SGEMM: C[M,N] (+)= A' @ B'
//   TA=0: A is [M,K] row-major. TA=1: A stored [K,M] (use A^T).
//   TB=0: B is [K,N] row-major. TB=1: B stored [N,K] (use B^T).
//   ACC=1: accumulate into C.
// Batched via blockIdx.z with element strides sA,sB,sC.
// K must be a multiple of 16 (true for all uses: 16/64/1024/2048).
// ---------------------------------------------------------------------------
template<int TA, int TB, int ACC>
__global__ __launch_bounds__(256)
void sgemm_kernel(const float* __restrict__ A, const float* __restrict__ Bp,
                  float* __restrict__ C, int M, int N, int K,
                  long sA, long sB, long sC)
{
    A  += (long)blockIdx.z * sA;
    Bp += (long)blockIdx.z * sB;
    C  += (long)blockIdx.z * sC;
    const int bi = blockIdx.y * 64;
    const int bj = blockIdx.x * 64;
    const int tid = threadIdx.x;

    __shared__ float As[16][65];
    __shared__ float Bs[16][65];

    float acc[4][4];
#pragma unroll
    for (int a = 0; a < 4; ++a)
#pragma unroll
        for (int b = 0; b < 4; ++b) acc[a][b] = 0.f;

    const int tr = tid >> 4;   // 0..15
    const int tc = tid & 15;   // 0..15

    for (int k0 = 0; k0 < K; k0 += 16) {
        // ---- load A tile: As[kk][i] = A'[bi+i][k0+kk]
        if (TA == 0) {
#pragma unroll
            for (int r = 0; r < 4; ++r) {
                int i  = (tid >> 4) + 16 * r;
                int kk = tid & 15;
                float v = 0.f;
                if (bi + i < M) v = A[(long)(bi + i) * K + k0 + kk];
                As[kk][i] = v;
            }
        } else {
#pragma unroll
            for (int r = 0; r < 4; ++r) {
                int kk = (tid >> 6) + 4 * r;
                int i  = tid & 63;
                float v = 0.f;
                if (bi + i < M) v = A[(long)(k0 + kk) * M + bi + i];
                As[kk][i] = v;
            }
        }
        // ---- load B tile: Bs[kk][j] = B'[k0+kk][bj+j]
        if (TB == 0) {
#pragma unroll
            for (int r = 0; r < 4; ++r) {
                int kk = (tid >> 6) + 4 * r;
                int j  = tid & 63;
                float v = 0.f;
                if (bj + j < N) v = Bp[(long)(k0 + kk) * N + bj + j];
                Bs[kk][j] = v;
            }
        } else {
#pragma unroll
            for (int r = 0; r < 4; ++r) {
                int j  = (tid >> 4) + 16 * r;
                int kk = tid & 15;
                float v = 0.f;
                if (bj + j < N) v = Bp[(long)(bj + j) * K + k0 + kk];
                Bs[kk][j] = v;
            }
        }
        __syncthreads();
#pragma unroll
        for (int kk = 0; kk < 16; ++kk) {
            float av[4], bv[4];
#pragma unroll
            for (int a = 0; a < 4; ++a) av[a] = As[kk][tr + 16 * a];
#pragma unroll
            for (int b = 0; b < 4; ++b) bv[b] = Bs[kk][tc + 16 * b];
#pragma unroll
            for (int a = 0; a < 4; ++a)
#pragma unroll
                for (int b = 0; b < 4; ++b)
                    acc[a][b] = fmaf(av[a], bv[b], acc[a][b]);
        }
        __syncthreads();
    }

#pragma unroll
    for (int a = 0; a < 4; ++a) {
        int i = bi + tr + 16 * a;
        if (i >= M) continue;
#pragma unroll
        for (int b = 0; b < 4; ++b) {
            int j = bj + tc + 16 * b;
            if (j >= N) continue;
            long idx = (long)i * N + j;
            if (ACC) C[idx] += acc[a][b]; else C[idx] = acc[a][b];
        }
    }
}

template<int TA, int TB, int ACC>
static inline void launch_gemm(const float* A, const float* Bp, float* C,
                               int M, int N, int K, long sA, long sB, long sC,
                               int batch, hipStream_t s)
{
    dim3 grid((N + 63) / 64, (M + 63) / 64, batch);
    sgemm_kernel<TA, TB, ACC><<<grid, dim3(256), 0, s>>>(A, Bp, C, M, N, K, sA, sB, sC);
}

// ---------------------------------------------------------------------------
// Elementwise helpers
// ---------------------------------------------------------------------------
__global__ __launch_bounds__(256)
void mul_inplace_kernel(float* __restrict__ a, const float* __restrict__ b, int n)
{
    int i = blockIdx.x * 256 + threadIdx.x;
    if (i < n) a[i] *= b[i];
}

// out[row, c] = v[row, c] * s[row]
__global__ __launch_bounds__(256)
void scale_rows_kernel(const float* __restrict__ v, const float* __restrict__ s,
                       float* __restrict__ out, int cols)
{
    int row = blockIdx.y;
    int c = blockIdx.x * 256 + threadIdx.x;
    long idx = (long)row * cols + c;
    out[idx] = v[idx] * s[row];
}

// ---------------------------------------------------------------------------
// Fused h kernel: one block per (b,i) row.
//   h_mix[i,j]   = z[i,j]*d1[j]  + zB[i,:]·A1[j,:]
//   h_scale[i,j] = zs[i,j]*d1s[j]+ zsB[i,:]·A1s[j,:]
//   h[i,j] = softplus(h_scale) * relu(h_mix / (||h_mix row||2 + 1e-8))
// h written in-place over z (safe: each block only touches its own row,
// reads complete before writes via two-pass structure).
// ---------------------------------------------------------------------------
__global__ __launch_bounds__(256)
void fuse_h_kernel(float* __restrict__ z, const float* __restrict__ zs,
                   const float* __restrict__ zB, const float* __restrict__ zsB,
                   const float* __restrict__ d1, const float* __restrict__ A1,
                   const float* __restrict__ d1s, const float* __restrict__ A1s)
{
    const int gi = blockIdx.x;          // 0..MT-1
    const int b  = gi / TT;
    const int tid = threadIdx.x;

    float* zrow        = z  + (long)gi * TT;
    const float* zsrow = zs + (long)gi * TT;
    const float* d1b   = d1  + (long)b * TT;
    const float* A1b   = A1  + (long)b * TT * RS;
    const float* d1sb  = d1s + (long)b * TT;
    const float* A1sb  = A1s + (long)b * TT * RS;

    __shared__ float hm[TT];       // 8 KB: h_mix row
    __shared__ float warp_s[4];

    float zBi[RS], zsBi[RS];
#pragma unroll
    for (int r = 0; r < RS; ++r) {
        zBi[r]  = zB[(long)gi * RS + r];
        zsBi[r] = zsB[(long)gi * RS + r];
    }

    float ss = 0.f;
    for (int j = tid; j < TT; j += 256) {
        float acc = zrow[j] * d1b[j];
#pragma unroll
        for (int r = 0; r < RS; ++r) acc = fmaf(zBi[r], A1b[(long)j * RS + r], acc);
        hm[j] = acc;
        ss = fmaf(acc, acc, ss);
    }
    // block reduce ss
#pragma unroll
    for (int off = 32; off > 0; off >>= 1) ss += __shfl_down(ss, off, 64);
    if ((tid & 63) == 0) warp_s[tid >> 6] = ss;
    __syncthreads();
    float total = warp_s[0] + warp_s[1] + warp_s[2] + warp_s[3];
    float inv = 1.f / (sqrtf(total) + 1e-8f);

    for (int j = tid; j < TT; j += 256) {
        float acc = zsrow[j] * d1sb[j];
#pragma unroll
        for (int r = 0; r < RS; ++r) acc = fmaf(zsBi[r], A1sb[(long)j * RS + r], acc);
        // stable softplus
        float sp = fmaxf(acc, 0.f) + log1pf(expf(-fabsf(acc)));
        float m = hm[j] * inv;
        zrow[j] = sp * (m > 0.f ? m : 0.f);   // h over z
    }
}

// ---------------------------------------------------------------------------
extern "C" void kernel_launch(void* const* d_in, const int* in_sizes, int n_in,
                              void* d_out, int out_size, void* d_ws, size_t ws_size,
                              hipStream_t stream)
{
    const float* x = (const float*)d_in[0];
    const float* W[27];
    for (int i = 1; i < 27; ++i) W[i] = (const float*)d_in[i];
    float* out = (float*)d_out;

    // --- workspace carve-up (bump allocator, 256B aligned) ---
    char* ws = (char*)d_ws;
    size_t off = 0;
    auto alloc = [&](size_t bytes) -> float* {
        float* p = (float*)(ws + off);
        off += (bytes + 255) & ~(size_t)255;
        return p;
    };
    const size_t bigBytes = (size_t)MT * DD * sizeof(float);     // 16 MB
    float* P0 = alloc(bigBytes);   // q -> q*mg -> later vd
    float* P1 = alloc(bigBytes);   // k -> later context
    float* P2 = alloc(bigBytes);   // qs -> qs*mgs
    float* P3 = alloc(bigBytes);   // ks
    float* P4 = alloc(bigBytes);   // mg/mgs temp -> v
    float* P5 = alloc(bigBytes);   // mvo
    float* tmp1 = alloc((size_t)MT * RR * sizeof(float));        // 1 MB stage-1
    float* z  = alloc((size_t)BB * TT * TT * sizeof(float));     // 33.5 MB (later h)
    float* zsb_mat = alloc((size_t)BB * TT * TT * sizeof(float));// 33.5 MB zs
    float* d1   = alloc((size_t)MT * sizeof(float));
    float* A1   = alloc((size_t)MT * RS * sizeof(float));
    float* B1m  = alloc((size_t)MT * RS * sizeof(float));
    float* d1s  = alloc((size_t)MT * sizeof(float));
    float* A1s  = alloc((size_t)MT * RS * sizeof(float));
    float* B1sm = alloc((size_t)MT * RS * sizeof(float));
    float* d2   = alloc((size_t)MT * sizeof(float));
    float* A2   = alloc((size_t)MT * RS * sizeof(float));
    float* B2m  = alloc((size_t)MT * RS * sizeof(float));
    float* zB   = alloc((size_t)MT * RS * sizeof(float));
    float* zsB  = alloc((size_t)MT * RS * sizeof(float));
    float* hB   = alloc((size_t)MT * RS * sizeof(float));
    float* A2tV = alloc((size_t)BB * RS * DD * sizeof(float));
    (void)ws_size; (void)in_sizes; (void)n_in; (void)out_size;

    const long sZ  = (long)TT * TT;
    const long sTD = (long)TT * DD;
    const long sTR = (long)TT * RS;

    // --- low-rank feature mixing (8 projections, weights shared over batch) ---
    auto lowrank = [&](const float* W1, const float* W2, float* dst) {
        launch_gemm<0,0,0>(x,    W1, tmp1, MT, RR, DD, 0, 0, 0, 1, stream);
        launch_gemm<0,0,0>(tmp1, W2, dst,  MT, DD, RR, 0, 0, 0, 1, stream);
    };
    lowrank(W[1],  W[2],  P0);   // q
    lowrank(W[3],  W[4],  P4);   // mg
    mul_inplace_kernel<<<MT*DD/256, 256, 0, stream>>>(P0, P4, MT*DD);  // qg
    lowrank(W[5],  W[6],  P1);   // k
    lowrank(W[7],  W[8],  P2);   // qs
    lowrank(W[9],  W[10], P4);   // mgs
    mul_inplace_kernel<<<MT*DD/256, 256, 0, stream>>>(P2, P4, MT*DD);  // qsg
    lowrank(W[11], W[12], P3);   // ks
    lowrank(W[13], W[14], P4);   // v
    lowrank(W[15], W[16], P5);   // mvo

    // --- DPLR generators: d/A/B for the three sequence mixings ---
    launch_gemm<0,0,0>(x, W[18], d1,   MT, 1,  DD, 0, 0, 0, 1, stream);
    launch_gemm<0,0,0>(x, W[19], A1,   MT, RS, DD, 0, 0, 0, 1, stream);
    launch_gemm<0,0,0>(x, W[20], B1m,  MT, RS, DD, 0, 0, 0, 1, stream);
    launch_gemm<0,0,0>(x, W[21], d1s,  MT, 1,  DD, 0, 0, 0, 1, stream);
    launch_gemm<0,0,0>(x, W[22], A1s,  MT, RS, DD, 0, 0, 0, 1, stream);
    launch_gemm<0,0,0>(x, W[23], B1sm, MT, RS, DD, 0, 0, 0, 1, stream);
    launch_gemm<0,0,0>(x, W[24], d2,   MT, 1,  DD, 0, 0, 0, 1, stream);
    launch_gemm<0,0,0>(x, W[25], A2,   MT, RS, DD, 0, 0, 0, 1, stream);
    launch_gemm<0,0,0>(x, W[26], B2m,  MT, RS, DD, 0, 0, 0, 1, stream);

    // --- scores: z = (q*mg) @ k^T, zs = (qs*mgs) @ ks^T  (batched NT) ---
    launch_gemm<0,1,0>(P0, P1, z,       TT, TT, DD, sTD, sTD, sZ, BB, stream);
    launch_gemm<0,1,0>(P2, P3, zsb_mat, TT, TT, DD, sTD, sTD, sZ, BB, stream);

    // --- zB = z @ B1m, zsB = zs @ B1sm (batched skinny NN) ---
    launch_gemm<0,0,0>(z,       B1m,  zB,  TT, RS, TT, sZ, sTR, sTR, BB, stream);
    launch_gemm<0,0,0>(zsb_mat, B1sm, zsB, TT, RS, TT, sZ, sTR, sTR, BB, stream);

    // --- fused DPLR-diag + norm + HyperGLU -> h (overwrites z) ---
    fuse_h_kernel<<<MT, 256, 0, stream>>>(z, zsb_mat, zB, zsB, d1, A1, d1s, A1s);
    float* h = z;

    // --- readout decomposition: context = h @ (d2⊙v) + hB @ (A2^T v) ---
    launch_gemm<0,0,0>(h, B2m, hB, TT, RS, TT, sZ, sTR, sTR, BB, stream);
    launch_gemm<1,0,0>(A2, P4, A2tV, RS, DD, TT, sTR, sTD, (long)RS*DD, BB, stream);
    scale_rows_kernel<<<dim3(DD/256, MT), 256, 0, stream>>>(P4, d2, P0, DD); // vd into P0
    launch_gemm<0,0,0>(h,  P0,   P1, TT, DD, TT, sZ, sTD, sTD, BB, stream);          // context
    launch_gemm<0,0,1>(hB, A2tV, P1, TT, DD, RS, sTR, (long)RS*DD, sTD, BB, stream); // += rank16

    // --- output: (context * mvo) @ Wo^T ---
    mul_inplace_kernel<<<MT*DD/256, 256, 0, stream>>>(P1, P5, MT*DD);
    launch_gemm<0,1,0>(P1, W[17], out, MT, DD, DD, 0, 0, 0, 1, stream);
}

// Round 2
// 766.001 us; speedup vs baseline: 5.8734x; 5.8734x over previous
//
#include <hip/hip_runtime.h>
#include <math.h>

#define BB 2
#define TT 2048
#define DD 1024
#define RS 16
#define MT (BB*TT)      // 4096 flattened rows
#define GLD 640         // stage-1 concat output width (611 used, padded)

typedef __attribute__((ext_vector_type(8))) short s16x8;
typedef __attribute__((ext_vector_type(4))) float f32x4;

__device__ __forceinline__ short f2bf(float f) {
    union { float f; unsigned u; } v; v.f = f;
    unsigned r = (v.u + 0x7fffu + ((v.u >> 16) & 1u)) >> 16;
    return (short)r;
}
__device__ __forceinline__ float bf2f(short s) {
    union { unsigned u; float f; } v; v.u = ((unsigned)(unsigned short)s) << 16;
    return v.f;
}

__device__ __forceinline__ void gload16(const void* g, void* l) {
    __builtin_amdgcn_global_load_lds((const __attribute__((address_space(1))) void*)g,
                                     (__attribute__((address_space(3))) void*)l, 16, 0, 0);
}

// ---------------------------------------------------------------------------
// bf16 MFMA GEMM, NT form: C[M,N] = A[M,K] @ Bt[N,K]^T, fp32 out.
// 128x128 tile, 4 waves (2x2), 16x16x32 MFMA, BK=32, global_load_lds staging.
// M,N multiples of 128; K multiple of 32.
// ---------------------------------------------------------------------------
__global__ __launch_bounds__(256)
void gemm_bf16_nt(const short* __restrict__ A, const short* __restrict__ Bt,
                  float* __restrict__ C, int K, int lda, int ldb, int ldc,
                  long sA, long sB, long sC)
{
    A  += (long)blockIdx.z * sA;
    Bt += (long)blockIdx.z * sB;
    C  += (long)blockIdx.z * sC;
    const int bi = blockIdx.y * 128, bj = blockIdx.x * 128;
    const int tid  = threadIdx.x;
    const int wv   = tid >> 6, lane = tid & 63;
    const int wr   = (wv >> 1) * 64, wc = (wv & 1) * 64;

    __shared__ __align__(16) short smem[8192];   // A tile [128][32] @0, B tile @4096
    short* Asm = smem;
    short* Bsm = smem + 4096;

    f32x4 acc[4][4];
#pragma unroll
    for (int m = 0; m < 4; ++m)
#pragma unroll
        for (int n = 0; n < 4; ++n) acc[m][n] = (f32x4){0.f, 0.f, 0.f, 0.f};

    const int srow = wv * 16 + (lane >> 2);   // staging row (+ p*64)
    const int skk  = (lane & 3) * 8;          // staging k offset (elements)
    const int frow = lane & 15;               // fragment row/col within 16
    const int kg   = (lane >> 4) * 8;         // fragment k offset within 32

    for (int k0 = 0; k0 < K; k0 += 32) {
#pragma unroll
        for (int p = 0; p < 2; ++p) {
            gload16(A  + (long)(bi + p*64 + srow) * lda + k0 + skk, Asm + p*2048 + wv*512);
            gload16(Bt + (long)(bj + p*64 + srow) * ldb + k0 + skk, Bsm + p*2048 + wv*512);
        }
        __syncthreads();
        s16x8 af[4], bfr[4];
#pragma unroll
        for (int m = 0; m < 4; ++m)
            af[m] = *(const s16x8*)&Asm[(wr + m*16 + frow) * 32 + kg];
#pragma unroll
        for (int n = 0; n < 4; ++n)
            bfr[n] = *(const s16x8*)&Bsm[(wc + n*16 + frow) * 32 + kg];
#pragma unroll
        for (int m = 0; m < 4; ++m)
#pragma unroll
            for (int n = 0; n < 4; ++n)
                acc[m][n] = __builtin_amdgcn_mfma_f32_16x16x32_bf16(af[m], bfr[n], acc[m][n], 0, 0, 0);
        __syncthreads();
    }

    const int col0 = lane & 15, row0 = (lane >> 4) * 4;
#pragma unroll
    for (int m = 0; m < 4; ++m) {
#pragma unroll
        for (int n = 0; n < 4; ++n) {
#pragma unroll
            for (int r = 0; r < 4; ++r) {
                int i = bi + wr + m*16 + row0 + r;
                int j = bj + wc + n*16 + col0;
                C[(long)i * ldc + j] = acc[m][n][r];
            }
        }
    }
}

static inline void gemm(const short* A, const short* Bt, float* C, int M, int N, int K,
                        int lda, int ldb, int ldc, long sA, long sB, long sC,
                        int batch, hipStream_t st)
{
    dim3 grid(N / 128, M / 128, batch);
    gemm_bf16_nt<<<grid, dim3(256), 0, st>>>(A, Bt, C, K, lda, ldb, ldc, sA, sB, sC);
}

// ---------------------------------------------------------------------------
// Weight concat / convert kernels
// ---------------------------------------------------------------------------
struct ConcatArgs { const float* p[17]; int col0[17]; int wid[17]; };

// WcatT[n][k] = W_s[k][c] (bf16), rows 611..639 zero. grid = 640 blocks.
__global__ __launch_bounds__(256)
void concat_w1_kernel(ConcatArgs a, short* __restrict__ WcatT)
{
    const int n = blockIdx.x;
    int s = -1, c = 0;
    for (int i = 0; i < 17; ++i)
        if (n >= a.col0[i] && n < a.col0[i] + a.wid[i]) { s = i; c = n - a.col0[i]; }
    for (int k = threadIdx.x; k < DD; k += 256)
        WcatT[(long)n * DD + k] = (s < 0) ? (short)0 : f2bf(a.p[s][(long)k * a.wid[s] + c]);
}

struct Ptrs8 { const float* p[8]; };

// W2catT[s][n][k] = W2_s[k][n] (bf16). grid (DD/64, 8), 256 thr, LDS transpose.
__global__ __launch_bounds__(256)
void concat_w2_kernel(Ptrs8 a, short* __restrict__ W2catT)
{
    const int s = blockIdx.y, n0 = blockIdx.x * 64;
    const int tx = threadIdx.x & 63, ty = threadIdx.x >> 6;
    __shared__ float t[64][65];
    const float* W2 = a.p[s];                       // [64][DD]
    for (int kk = ty; kk < 64; kk += 4) t[kk][tx] = W2[(long)kk * DD + n0 + tx];
    __syncthreads();
    for (int n = ty; n < 64; n += 4)
        W2catT[((long)s * DD + n0 + n) * 64 + tx] = f2bf(t[tx][n]);
}

__global__ __launch_bounds__(256)
void f2bf_vec_kernel(const float* __restrict__ in, short* __restrict__ o, long n4)
{
    long i = (long)blockIdx.x * 256 + threadIdx.x;
    if (i < n4) {
        float4 v = ((const float4*)in)[i];
        short4 r; r.x = f2bf(v.x); r.y = f2bf(v.y); r.z = f2bf(v.z); r.w = f2bf(v.w);
        ((short4*)o)[i] = r;
    }
}

__global__ __launch_bounds__(256)
void ewmul_bf16_kernel(const float* __restrict__ a, const float* __restrict__ b,
                       short* __restrict__ o, long n4)
{
    long i = (long)blockIdx.x * 256 + threadIdx.x;
    if (i < n4) {
        float4 x = ((const float4*)a)[i];
        float4 y = ((const float4*)b)[i];
        short4 r; r.x = f2bf(x.x * y.x); r.y = f2bf(x.y * y.y);
        r.z = f2bf(x.z * y.z); r.w = f2bf(x.w * y.w);
        ((short4*)o)[i] = r;
    }
}

// Gb over [MT][512] from G[row][0..511] (ld GLD)
__global__ __launch_bounds__(256)
void gb_kernel(const float* __restrict__ G, short* __restrict__ Gb)
{
    long i = (long)blockIdx.x * 256 + threadIdx.x;   // MT*512
    long row = i >> 9; int c = (int)(i & 511);
    Gb[i] = f2bf(G[row * GLD + c]);
}

// ---------------------------------------------------------------------------
// Skinny rank-16: out[i][r] = sum_j Z[i][j] * G[(b*TT+j)][gcol+r]
// ---------------------------------------------------------------------------
template<int ISBF>
__global__ __launch_bounds__(256)
void rowmat16_kernel(const void* __restrict__ Zv, const float* __restrict__ G,
                     int gcol, float* __restrict__ outp)
{
    const int gi = blockIdx.x, b = gi / TT, tid = threadIdx.x;
    const float* Gb = G + (long)b * TT * GLD + gcol;
    float acc[RS];
#pragma unroll
    for (int r = 0; r < RS; ++r) acc[r] = 0.f;

    if (ISBF) {
        const short* zrow = (const short*)Zv + (long)gi * TT;
        for (int j = tid; j < TT; j += 256) {
            float zv = bf2f(zrow[j]);
            const float* Bj = Gb + (long)j * GLD;
#pragma unroll
            for (int r = 0; r < RS; ++r) acc[r] = fmaf(zv, Bj[r], acc[r]);
        }
    } else {
        const float* zrow = (const float*)Zv + (long)gi * TT;
        for (int j = tid; j < TT; j += 256) {
            float zv = zrow[j];
            const float* Bj = Gb + (long)j * GLD;
#pragma unroll
            for (int r = 0; r < RS; ++r) acc[r] = fmaf(zv, Bj[r], acc[r]);
        }
    }
#pragma unroll
    for (int off = 32; off; off >>= 1)
#pragma unroll
        for (int r = 0; r < RS; ++r) acc[r] += __shfl_down(acc[r], off, 64);
    __shared__ float red[4][RS];
    if ((tid & 63) == 0) {
        int w = tid >> 6;
#pragma unroll
        for (int r = 0; r < RS; ++r) red[w][r] = acc[r];
    }
    __syncthreads();
    if (tid < RS)
        outp[(long)gi * RS + tid] = red[0][tid] + red[1][tid] + red[2][tid] + red[3][tid];
}

// ---------------------------------------------------------------------------
// Fused DPLR-diag + L2 norm + HyperGLU -> h (bf16)
// ---------------------------------------------------------------------------
__global__ __launch_bounds__(256)
void fuse_h_kernel(const float* __restrict__ z, const float* __restrict__ zs,
                   const float* __restrict__ zB, const float* __restrict__ zsB,
                   const float* __restrict__ G, short* __restrict__ h)
{
    const int gi = blockIdx.x, b = gi / TT, tid = threadIdx.x;
    const float* zrow  = z  + (long)gi * TT;
    const float* zsrow = zs + (long)gi * TT;
    const float* Gb    = G + (long)b * TT * GLD;

    __shared__ float hm[TT];
    __shared__ float warp_s[4];

    float zBi[RS], zsBi[RS];
#pragma unroll
    for (int r = 0; r < RS; ++r) {
        zBi[r]  = zB[(long)gi * RS + r];
        zsBi[r] = zsB[(long)gi * RS + r];
    }

    float ss = 0.f;
    for (int j = tid; j < TT; j += 256) {
        const float* grow = Gb + (long)j * GLD;
        float acc = zrow[j] * grow[512];
#pragma unroll
        for (int r = 0; r < RS; ++r) acc = fmaf(zBi[r], grow[513 + r], acc);
        hm[j] = acc;
        ss = fmaf(acc, acc, ss);
    }
#pragma unroll
    for (int off = 32; off; off >>= 1) ss += __shfl_down(ss, off, 64);
    if ((tid & 63) == 0) warp_s[tid >> 6] = ss;
    __syncthreads();
    float total = warp_s[0] + warp_s[1] + warp_s[2] + warp_s[3];
    float inv = 1.f / (sqrtf(total) + 1e-8f);

    for (int j = tid; j < TT; j += 256) {
        const float* grow = Gb + (long)j * GLD;
        float acc = zsrow[j] * grow[545];
#pragma unroll
        for (int r = 0; r < RS; ++r) acc = fmaf(zsBi[r], grow[546 + r], acc);
        float sp = fmaxf(acc, 0.f) + log1pf(expf(-fabsf(acc)));
        float m = hm[j] * inv;
        h[(long)gi * TT + j] = f2bf(sp * (m > 0.f ? m : 0.f));
    }
}

// ---------------------------------------------------------------------------
// vdT[b][d][t] = bf16(v[b][t][d] * d2[b][t]),  d2 = G col 578
// ---------------------------------------------------------------------------
__global__ __launch_bounds__(256)
void vdt_kernel(const float* __restrict__ v, const float* __restrict__ G,
                short* __restrict__ o)
{
    const int t0 = blockIdx.x * 32, d0 = blockIdx.y * 32, b = blockIdx.z;
    const int tx = threadIdx.x & 31, ty = threadIdx.x >> 5;   // 32 x 8
    __shared__ float tile[32][33];
    for (int s = 0; s < 32; s += 8) {
        int t = t0 + ty + s;
        float d2v = G[((long)b * TT + t) * GLD + 578];
        tile[ty + s][tx] = v[((long)b * TT + t) * DD + d0 + tx] * d2v;
    }
    __syncthreads();
    for (int s = 0; s < 32; s += 8) {
        int d = d0 + ty + s;
        o[((long)b * DD + d) * TT + t0 + tx] = f2bf(tile[tx][ty + s]);
    }
}

// ---------------------------------------------------------------------------
// A2tV[b][r][d] = sum_t A2[b][t][r] * v[b][t][d]   (A2 = G cols 579..594)
// ---------------------------------------------------------------------------
__global__ __launch_bounds__(256)
void zero_kernel(float* __restrict__ p, long n)
{
    long i = (long)blockIdx.x * 256 + threadIdx.x;
    if (i < n) p[i] = 0.f;
}

__global__ __launch_bounds__(256)
void a2tv_kernel(const float* __restrict__ v, const float* __restrict__ G,
                 float* __restrict__ o)
{
    const int d0 = blockIdx.x * 64, ks = blockIdx.y, b = blockIdx.z;
    const int dl = threadIdx.x & 63, tg = threadIdx.x >> 6;
    float acc[RS];
#pragma unroll
    for (int r = 0; r < RS; ++r) acc[r] = 0.f;
    for (int tt = 0; tt < 64; ++tt) {
        int t = ks * 256 + tg * 64 + tt;
        const float* grow = G + ((long)b * TT + t) * GLD;
        float vv = v[((long)b * TT + t) * DD + d0 + dl];
#pragma unroll
        for (int r = 0; r < RS; ++r) acc[r] = fmaf(grow[579 + r], vv, acc[r]);
    }
    __shared__ float red[4][RS][64];
#pragma unroll
    for (int r = 0; r < RS; ++r) red[tg][r][dl] = acc[r];
    __syncthreads();
    for (int q = threadIdx.x; q < RS * 64; q += 256) {
        int r = q >> 6, d = q & 63;
        float s = red[0][r][d] + red[1][r][d] + red[2][r][d] + red[3][r][d];
        atomicAdd(&o[((long)b * RS + r) * DD + d0 + d], s);
    }
}

// ---------------------------------------------------------------------------
// cm[i][d] = bf16( (ctx[i][d] + sum_r hB[i][r]*A2tV[b][r][d]) * mvo[i][d] )
// ---------------------------------------------------------------------------
__global__ __launch_bounds__(256)
void fuse_out_kernel(const float* __restrict__ ctx, const float* __restrict__ mvo,
                     const float* __restrict__ hB, const float* __restrict__ A2tV,
                     short* __restrict__ cm)
{
    long i = (long)blockIdx.x * 256 + threadIdx.x;   // MT*DD
    long row = i >> 10; int d = (int)(i & 1023); int b = (int)(row >> 11);
    float acc = ctx[i];
    const float* hb = hB + row * RS;
#pragma unroll
    for (int r = 0; r < RS; ++r)
        acc = fmaf(hb[r], A2tV[((long)b * RS + r) * DD + d], acc);
    cm[i] = f2bf(acc * mvo[i]);
}

// ---------------------------------------------------------------------------
extern "C" void kernel_launch(void* const* d_in, const int* in_sizes, int n_in,
                              void* d_out, int out_size, void* d_ws, size_t ws_size,
                              hipStream_t stream)
{
    (void)in_sizes; (void)n_in; (void)out_size; (void)ws_size;
    const float* x = (const float*)d_in[0];
    const float* W[27];
    for (int i = 1; i < 27; ++i) W[i] = (const float*)d_in[i];
    float* out = (float*)d_out;

    char* ws = (char*)d_ws;
    size_t off = 0;
    auto alloc = [&](size_t bytes) -> void* {
        void* p = ws + off; off += (bytes + 255) & ~(size_t)255; return p;
    };
    short* xb    = (short*)alloc((size_t)MT * DD * 2);       // -> VDT later
    short* WcatT = (short*)alloc((size_t)GLD * DD * 2);
    short* W2catT= (short*)alloc((size_t)8 * DD * 64 * 2);
    short* Wob   = (short*)alloc((size_t)DD * DD * 2);
    float* G     = (float*)alloc((size_t)MT * GLD * 4);
    short* Gb    = (short*)alloc((size_t)MT * 512 * 2);
    float* S0    = (float*)alloc((size_t)MT * DD * 4);
    float* S1    = (float*)alloc((size_t)MT * DD * 4);
    short* QG    = (short*)alloc((size_t)MT * DD * 2);       // -> cm later
    short* KB    = (short*)alloc((size_t)MT * DD * 2);       // -> h (spans KB+KSB)
    short* KSB   = (short*)alloc((size_t)MT * DD * 2);
    short* QSG   = (short*)alloc((size_t)MT * DD * 2);
    float* z     = (float*)alloc((size_t)BB * TT * TT * 4);
    float* zsm   = (float*)alloc((size_t)BB * TT * TT * 4);
    float* zB    = (float*)alloc((size_t)MT * RS * 4);
    float* zsB   = (float*)alloc((size_t)MT * RS * 4);
    float* hB    = (float*)alloc((size_t)MT * RS * 4);
    float* A2tV  = (float*)alloc((size_t)BB * RS * DD * 4);
    short* VDT = xb;     // alias: xb dead after stage-1 GEMM
    short* h   = KB;     // alias: KB+KSB (contiguous 16MB) dead after zs GEMM
    short* cm  = QG;     // alias: QG dead after z GEMM

    const long sTD = (long)TT * DD, sTT = (long)TT * TT;
    const long n4 = (long)MT * DD / 4;

    // --- convert x to bf16 ---
    f2bf_vec_kernel<<<n4 / 256, 256, 0, stream>>>(x, xb, n4);

    // --- build weight operands ---
    ConcatArgs ca;
    {
        const int w1idx[8] = {1, 3, 5, 7, 9, 11, 13, 15};
        for (int s = 0; s < 8; ++s) { ca.p[s] = W[w1idx[s]]; ca.col0[s] = s * 64; ca.wid[s] = 64; }
        const int didx[9] = {18, 19, 20, 21, 22, 23, 24, 25, 26};
        const int dcol[9] = {512, 513, 529, 545, 546, 562, 578, 579, 595};
        const int dwid[9] = {1, 16, 16, 1, 16, 16, 1, 16, 16};
        for (int s = 0; s < 9; ++s) { ca.p[8 + s] = W[didx[s]]; ca.col0[8 + s] = dcol[s]; ca.wid[8 + s] = dwid[s]; }
    }
    concat_w1_kernel<<<GLD, 256, 0, stream>>>(ca, WcatT);
    Ptrs8 p8;
    {
        const int w2idx[8] = {2, 4, 6, 8, 10, 12, 14, 16};
        for (int s = 0; s < 8; ++s) p8.p[s] = W[w2idx[s]];
    }
    concat_w2_kernel<<<dim3(DD / 64, 8), 256, 0, stream>>>(p8, W2catT);
    f2bf_vec_kernel<<<((long)DD * DD / 4) / 256, 256, 0, stream>>>(W[17], Wob, (long)DD * DD / 4);

    // --- stage-1: G[4096,640] = xb @ WcatT^T (also produces all DPLR gens) ---
    gemm(xb, WcatT, G, MT, GLD, DD, DD, DD, GLD, 0, 0, 0, 1, stream);
    gb_kernel<<<MT * 512 / 256, 256, 0, stream>>>(G, Gb);

    // --- stage-2: 8 GEMMs [4096,1024,64]; A = Gb col-slice (lda 512) ---
    auto stage2 = [&](int s, float* dst) {
        gemm(Gb + s * 64, W2catT + (long)s * DD * 64, dst, MT, DD, 64, 512, 64, DD, 0, 0, 0, 1, stream);
    };
    stage2(0, S0);                                                    // q
    stage2(1, S1);                                                    // mg
    ewmul_bf16_kernel<<<n4 / 256, 256, 0, stream>>>(S0, S1, QG, n4);  // qg
    stage2(2, S0);                                                    // k
    f2bf_vec_kernel<<<n4 / 256, 256, 0, stream>>>(S0, KB, n4);        // kb
    stage2(3, S0);                                                    // qs
    stage2(4, S1);                                                    // mgs
    ewmul_bf16_kernel<<<n4 / 256, 256, 0, stream>>>(S0, S1, QSG, n4); // qsg
    stage2(5, S0);                                                    // ks
    f2bf_vec_kernel<<<n4 / 256, 256, 0, stream>>>(S0, KSB, n4);       // ksb
    stage2(6, S0);                                                    // v (stays in S0)
    stage2(7, S1);                                                    // mvo (stays in S1)

    // --- vdT + A2tV (both read v=S0) ---
    vdt_kernel<<<dim3(TT / 32, DD / 32, BB), 256, 0, stream>>>(S0, G, VDT);
    zero_kernel<<<(BB * RS * DD + 255) / 256, 256, 0, stream>>>(A2tV, (long)BB * RS * DD);
    a2tv_kernel<<<dim3(DD / 64, 8, BB), 256, 0, stream>>>(S0, G, A2tV);

    // --- scores: z = qg @ kb^T, zs = qsg @ ksb^T (batched NT) ---
    gemm(QG,  KB,  z,   TT, TT, DD, DD, DD, TT, sTD, sTD, sTT, BB, stream);
    gemm(QSG, KSB, zsm, TT, TT, DD, DD, DD, TT, sTD, sTD, sTT, BB, stream);

    // --- zB = z @ B1 (col 529), zsB = zs @ B1s (col 562) ---
    rowmat16_kernel<0><<<MT, 256, 0, stream>>>(z,   G, 529, zB);
    rowmat16_kernel<0><<<MT, 256, 0, stream>>>(zsm, G, 562, zsB);

    // --- fused DPLR-diag + norm + HyperGLU -> h (bf16, over KB/KSB) ---
    fuse_h_kernel<<<MT, 256, 0, stream>>>(z, zsm, zB, zsB, G, h);

    // --- hB = h @ B2 (col 595) ---
    rowmat16_kernel<1><<<MT, 256, 0, stream>>>(h, G, 595, hB);

    // --- context = h @ vdT^T  -> S0 ---
    gemm(h, VDT, S0, TT, DD, TT, TT, TT, DD, sTT, (long)DD * TT, sTD, BB, stream);

    // --- cm = bf16((context + hB@A2tV) * mvo) ---
    fuse_out_kernel<<<n4 * 4 / 256, 256, 0, stream>>>(S0, S1, hB, A2tV, cm);

    // --- out = cm @ Wo^T ---
    gemm(cm, Wob, out, MT, DD, DD, DD, DD, DD, 0, 0, 0, 1, stream);
}

// Round 3
// 449.452 us; speedup vs baseline: 10.0101x; 1.7043x over previous
//
#include <hip/hip_runtime.h>
#include <math.h>

#define BB 2
#define TT 2048
#define DD 1024
#define RS 16
#define MT (BB*TT)      // 4096 flattened rows
#define GLD 640         // stage-1 concat output width (611 used, padded)
#define KAUG 1056       // 1024 + 16 (zB/A1) + 16 zero pad; multiple of 32

typedef __attribute__((ext_vector_type(8))) short s16x8;
typedef __attribute__((ext_vector_type(4))) float f32x4;

__device__ __forceinline__ short f2bf(float f) {
    union { float f; unsigned u; } v; v.f = f;
    unsigned r = (v.u + 0x7fffu + ((v.u >> 16) & 1u)) >> 16;
    return (short)r;
}
__device__ __forceinline__ float bf2f(short s) {
    union { unsigned u; float f; } v; v.u = ((unsigned)(unsigned short)s) << 16;
    return v.f;
}

__device__ __forceinline__ void gload16(const void* g, void* l) {
    __builtin_amdgcn_global_load_lds((const __attribute__((address_space(1))) void*)g,
                                     (__attribute__((address_space(3))) void*)l, 16, 0, 0);
}

// ---------------------------------------------------------------------------
// Shared 128x128 NT tile core: acc = A[bi:bi+128, :K] @ Bt[bj:bj+128, :K]^T
// 4 waves (2x2), 16x16x32 bf16 MFMA, BK=32, global_load_lds staging.
// ---------------------------------------------------------------------------
__device__ __forceinline__ void gemm_core128(const short* __restrict__ A,
                                             const short* __restrict__ Bt,
                                             int K, int lda, int ldb,
                                             int bi, int bj, short* smem,
                                             f32x4 (&acc)[4][4])
{
    const int tid = threadIdx.x;
    const int wv = tid >> 6, lane = tid & 63;
    const int wr = (wv >> 1) * 64, wc = (wv & 1) * 64;
    short* Asm = smem;
    short* Bsm = smem + 4096;

#pragma unroll
    for (int m = 0; m < 4; ++m)
#pragma unroll
        for (int n = 0; n < 4; ++n) acc[m][n] = (f32x4){0.f, 0.f, 0.f, 0.f};

    const int srow = wv * 16 + (lane >> 2);
    const int skk  = (lane & 3) * 8;
    const int frow = lane & 15;
    const int kg   = (lane >> 4) * 8;

    for (int k0 = 0; k0 < K; k0 += 32) {
#pragma unroll
        for (int p = 0; p < 2; ++p) {
            gload16(A  + (long)(bi + p*64 + srow) * lda + k0 + skk, Asm + p*2048 + wv*512);
            gload16(Bt + (long)(bj + p*64 + srow) * ldb + k0 + skk, Bsm + p*2048 + wv*512);
        }
        __syncthreads();
        s16x8 af[4], bfr[4];
#pragma unroll
        for (int m = 0; m < 4; ++m)
            af[m] = *(const s16x8*)&Asm[(wr + m*16 + frow) * 32 + kg];
#pragma unroll
        for (int n = 0; n < 4; ++n)
            bfr[n] = *(const s16x8*)&Bsm[(wc + n*16 + frow) * 32 + kg];
#pragma unroll
        for (int m = 0; m < 4; ++m)
#pragma unroll
            for (int n = 0; n < 4; ++n)
                acc[m][n] = __builtin_amdgcn_mfma_f32_16x16x32_bf16(af[m], bfr[n], acc[m][n], 0, 0, 0);
        __syncthreads();
    }
}

// Generic batched NT GEMM; STORE 0 = fp32 out, 1 = bf16 out.
template<int STORE>
__global__ __launch_bounds__(256)
void gemm_nt(const short* __restrict__ A, const short* __restrict__ Bt,
             void* __restrict__ Cv, int K, int lda, int ldb, int ldc,
             long sA, long sB, long sC)
{
    A  += (long)blockIdx.z * sA;
    Bt += (long)blockIdx.z * sB;
    const int bi = blockIdx.y * 128, bj = blockIdx.x * 128;
    __shared__ __align__(16) short smem[8192];
    f32x4 acc[4][4];
    gemm_core128(A, Bt, K, lda, ldb, bi, bj, smem, acc);

    const int lane = threadIdx.x & 63, wv = threadIdx.x >> 6;
    const int wr = (wv >> 1) * 64, wc = (wv & 1) * 64;
    const int col0 = lane & 15, row0 = (lane >> 4) * 4;
#pragma unroll
    for (int m = 0; m < 4; ++m)
#pragma unroll
        for (int n = 0; n < 4; ++n)
#pragma unroll
            for (int r = 0; r < 4; ++r) {
                int i = bi + wr + m*16 + row0 + r;
                int j = bj + wc + n*16 + col0;
                if (STORE == 0)
                    ((float*)Cv + (long)blockIdx.z * sC)[(long)i * ldc + j] = acc[m][n][r];
                else
                    ((short*)Cv + (long)blockIdx.z * sC)[(long)i * ldc + j] = f2bf(acc[m][n][r]);
            }
}

// hm/hs producer: blockIdx.z selects (batch, gate-vs-scale); bf16 out.
__global__ __launch_bounds__(256)
void hmhs_kernel(const short* __restrict__ QGaug, const short* __restrict__ QSGaug,
                 const short* __restrict__ KBaug, const short* __restrict__ KSBaug,
                 short* __restrict__ hm, short* __restrict__ hs)
{
    const int b = blockIdx.z & 1, which = blockIdx.z >> 1;
    const short* A  = (which ? QSGaug : QGaug) + (long)b * TT * KAUG;
    const short* Bt = (which ? KSBaug : KBaug) + (long)b * TT * KAUG;
    short* C = (which ? hs : hm) + (long)b * TT * TT;
    const int bi = blockIdx.y * 128, bj = blockIdx.x * 128;
    __shared__ __align__(16) short smem[8192];
    f32x4 acc[4][4];
    gemm_core128(A, Bt, KAUG, KAUG, KAUG, bi, bj, smem, acc);

    const int lane = threadIdx.x & 63, wv = threadIdx.x >> 6;
    const int wr = (wv >> 1) * 64, wc = (wv & 1) * 64;
    const int col0 = lane & 15, row0 = (lane >> 4) * 4;
#pragma unroll
    for (int m = 0; m < 4; ++m)
#pragma unroll
        for (int n = 0; n < 4; ++n)
#pragma unroll
            for (int r = 0; r < 4; ++r) {
                int i = bi + wr + m*16 + row0 + r;
                int j = bj + wc + n*16 + col0;
                C[(long)i * TT + j] = f2bf(acc[m][n][r]);
            }
}

// ---------------------------------------------------------------------------
// Stage-2 multi-slice GEMM (K=64): q/mg/k/qs/mgs/ks/v/mvo with fused epilogues.
// epi 0: fp32 out. 1: bf16 out. 2: bf16(acc * aux[i*DD+j]). 3: dual store
//        (plain bf16 ldc DD + bf16(acc * rowscale[i]) ldc KAUG).
// ---------------------------------------------------------------------------
struct S2Slice {
    int s; int epi; int ldcS;
    float* outF; short* outS; short* outS2;
    const float* aux; const float* rs;
};
struct S2Args { S2Slice sl[6]; };

__global__ __launch_bounds__(256)
void stage2_kernel(const short* __restrict__ Gb, const short* __restrict__ W2,
                   S2Args args)
{
    const S2Slice sl = args.sl[blockIdx.z];
    const short* A  = Gb + sl.s * 64;                 // lda GLD
    const short* Bt = W2 + (long)sl.s * DD * 64;      // ldb 64
    const int bi = blockIdx.y * 128, bj = blockIdx.x * 128;
    __shared__ __align__(16) short smem[8192];
    f32x4 acc[4][4];
    gemm_core128(A, Bt, 64, GLD, 64, bi, bj, smem, acc);

    const int lane = threadIdx.x & 63, wv = threadIdx.x >> 6;
    const int wr = (wv >> 1) * 64, wc = (wv & 1) * 64;
    const int col0 = lane & 15, row0 = (lane >> 4) * 4;
#pragma unroll
    for (int m = 0; m < 4; ++m)
#pragma unroll
        for (int n = 0; n < 4; ++n)
#pragma unroll
            for (int r = 0; r < 4; ++r) {
                int i = bi + wr + m*16 + row0 + r;
                int j = bj + wc + n*16 + col0;
                float val = acc[m][n][r];
                if (sl.epi == 0) {
                    sl.outF[(long)i * DD + j] = val;
                } else if (sl.epi == 1) {
                    sl.outS[(long)i * DD + j] = f2bf(val);
                } else if (sl.epi == 2) {
                    sl.outS[(long)i * sl.ldcS + j] = f2bf(val * sl.aux[(long)i * DD + j]);
                } else {
                    sl.outS2[(long)i * DD + j] = f2bf(val);
                    sl.outS[(long)i * sl.ldcS + j] = f2bf(val * sl.rs[i]);
                }
            }
}

// ---------------------------------------------------------------------------
// Weight prep (unchanged from round 2)
// ---------------------------------------------------------------------------
struct ConcatArgs { const float* p[17]; int col0[17]; int wid[17]; };

__global__ __launch_bounds__(256)
void concat_w1_kernel(ConcatArgs a, short* __restrict__ WcatT)
{
    const int n = blockIdx.x;
    int s = -1, c = 0;
    for (int i = 0; i < 17; ++i)
        if (n >= a.col0[i] && n < a.col0[i] + a.wid[i]) { s = i; c = n - a.col0[i]; }
    for (int k = threadIdx.x; k < DD; k += 256)
        WcatT[(long)n * DD + k] = (s < 0) ? (short)0 : f2bf(a.p[s][(long)k * a.wid[s] + c]);
}

struct Ptrs8 { const float* p[8]; };

__global__ __launch_bounds__(256)
void concat_w2_kernel(Ptrs8 a, short* __restrict__ W2catT)
{
    const int s = blockIdx.y, n0 = blockIdx.x * 64;
    const int tx = threadIdx.x & 63, ty = threadIdx.x >> 6;
    __shared__ float t[64][65];
    const float* W2 = a.p[s];
    for (int kk = ty; kk < 64; kk += 4) t[kk][tx] = W2[(long)kk * DD + n0 + tx];
    __syncthreads();
    for (int n = ty; n < 64; n += 4)
        W2catT[((long)s * DD + n0 + n) * 64 + tx] = f2bf(t[tx][n]);
}

__global__ __launch_bounds__(256)
void f2bf_vec_kernel(const float* __restrict__ in, short* __restrict__ o, long n4)
{
    long i = (long)blockIdx.x * 256 + threadIdx.x;
    if (i < n4) {
        float4 v = ((const float4*)in)[i];
        short4 r; r.x = f2bf(v.x); r.y = f2bf(v.y); r.z = f2bf(v.z); r.w = f2bf(v.w);
        ((short4*)o)[i] = r;
    }
}

// ---------------------------------------------------------------------------
// genprep: SoA-extract DPLR generators from G + fill aug constants/pads.
// ---------------------------------------------------------------------------
__global__ __launch_bounds__(256)
void genprep_kernel(const float* __restrict__ G, float* __restrict__ d1,
                    float* __restrict__ d1s, float* __restrict__ d2,
                    float* __restrict__ B1T, float* __restrict__ B1sT,
                    short* __restrict__ B2T, float* __restrict__ A2T,
                    short* __restrict__ QGaug, short* __restrict__ QSGaug,
                    short* __restrict__ KBaug, short* __restrict__ KSBaug)
{
    const int i = blockIdx.x * 256 + threadIdx.x;
    const float* g = G + (long)i * GLD;
    d1[i]  = g[512];
    d1s[i] = g[545];
    d2[i]  = g[578];
#pragma unroll
    for (int r = 0; r < RS; ++r) {
        KBaug [(long)i * KAUG + 1024 + r] = f2bf(g[513 + r]);
        KSBaug[(long)i * KAUG + 1024 + r] = f2bf(g[546 + r]);
        B1T [(long)r * MT + i] = g[529 + r];
        B1sT[(long)r * MT + i] = g[562 + r];
        A2T [(long)r * MT + i] = g[579 + r];
        B2T [(long)r * MT + i] = f2bf(g[595 + r]);
        KBaug [(long)i * KAUG + 1040 + r] = 0;
        KSBaug[(long)i * KAUG + 1040 + r] = 0;
        QGaug [(long)i * KAUG + 1040 + r] = 0;
        QSGaug[(long)i * KAUG + 1040 + r] = 0;
    }
}

__global__ __launch_bounds__(256)
void zero_kernel(float* __restrict__ p, long n)
{
    long i = (long)blockIdx.x * 256 + threadIdx.x;
    if (i < n) p[i] = 0.f;
}

// ---------------------------------------------------------------------------
// C1[b][d][r] = sum_t kb[b][t][d] * B1T[r][b*TT+t]   (atomic k-split)
// ---------------------------------------------------------------------------
__global__ __launch_bounds__(256)
void c1_kernel(const short* __restrict__ kb, const float* __restrict__ BT,
               float* __restrict__ C1)
{
    const int d0 = blockIdx.x * 64, t0 = blockIdx.y * 256, b = blockIdx.z;
    const int dl = threadIdx.x & 63, tg = threadIdx.x >> 6;
    float acc[RS];
#pragma unroll
    for (int r = 0; r < RS; ++r) acc[r] = 0.f;
    for (int tt = 0; tt < 64; ++tt) {
        int t = t0 + tg * 64 + tt;
        float kv = bf2f(kb[((long)b * TT + t) * DD + d0 + dl]);
#pragma unroll
        for (int r = 0; r < RS; ++r)
            acc[r] = fmaf(kv, BT[(long)r * MT + b * TT + t], acc[r]);
    }
    __shared__ float red[4][RS][64];
#pragma unroll
    for (int r = 0; r < RS; ++r) red[tg][r][dl] = acc[r];
    __syncthreads();
    for (int q = threadIdx.x; q < RS * 64; q += 256) {
        int r = q >> 6, d = q & 63;
        float s = red[0][r][d] + red[1][r][d] + red[2][r][d] + red[3][r][d];
        atomicAdd(&C1[((long)b * DD + d0 + d) * RS + r], s);
    }
}

__global__ __launch_bounds__(256)
void c1conv_kernel(const float* __restrict__ C1, const float* __restrict__ C1s,
                   short* __restrict__ C1b, short* __restrict__ C1sb)
{
    int i = blockIdx.x * 256 + threadIdx.x;   // BB*DD*RS = 32768
    C1b[i]  = f2bf(C1[i]);
    C1sb[i] = f2bf(C1s[i]);
}

// zB[i][:] = qg[i][:1024] @ C1b[b]  -> written into aug cols 1024..1039
__global__ __launch_bounds__(256)
void zb_kernel(short* __restrict__ aug, const short* __restrict__ C1b)
{
    const int gi = blockIdx.x, b = gi >> 11, tid = threadIdx.x;
    const short* qrow = aug + (long)gi * KAUG;
    const short* c1 = C1b + (long)b * DD * RS;
    float acc[RS];
#pragma unroll
    for (int r = 0; r < RS; ++r) acc[r] = 0.f;
#pragma unroll
    for (int c = 0; c < 4; ++c) {
        int d = tid + 256 * c;
        float q = bf2f(qrow[d]);
        const short* cr = c1 + (long)d * RS;
#pragma unroll
        for (int r = 0; r < RS; ++r) acc[r] = fmaf(q, bf2f(cr[r]), acc[r]);
    }
#pragma unroll
    for (int r = 0; r < RS; ++r)
#pragma unroll
        for (int off = 32; off; off >>= 1) acc[r] += __shfl_down(acc[r], off, 64);
    __shared__ float red[4][RS];
    if ((tid & 63) == 0)
#pragma unroll
        for (int r = 0; r < RS; ++r) red[tid >> 6][r] = acc[r];
    __syncthreads();
    if (tid < RS)
        aug[(long)gi * KAUG + 1024 + tid] =
            f2bf(red[0][tid] + red[1][tid] + red[2][tid] + red[3][tid]);
}

// ---------------------------------------------------------------------------
// fuse: L2-norm(hm row) + softplus(hs)*relu -> h bf16; hB = h row @ B2 (SoA)
// ---------------------------------------------------------------------------
__global__ __launch_bounds__(256)
void fuse_h3_kernel(const short* __restrict__ hm, const short* __restrict__ hs,
                    const short* __restrict__ B2T, short* __restrict__ h,
                    float* __restrict__ hB)
{
    const int i = blockIdx.x, b = blockIdx.y, tid = threadIdx.x;
    const long base = ((long)b * TT + i) * TT;
    const short* hmr = hm + base;
    const short* hsr = hs + base;

    float hmv[8]; float ss = 0.f;
#pragma unroll
    for (int c = 0; c < 8; ++c) {
        float v = bf2f(hmr[tid + 256 * c]);
        hmv[c] = v; ss = fmaf(v, v, ss);
    }
#pragma unroll
    for (int off = 32; off; off >>= 1) ss += __shfl_down(ss, off, 64);
    __shared__ float w4[4];
    if ((tid & 63) == 0) w4[tid >> 6] = ss;
    __syncthreads();
    const float inv = 1.f / (sqrtf(w4[0] + w4[1] + w4[2] + w4[3]) + 1e-8f);

    float hb[RS];
#pragma unroll
    for (int r = 0; r < RS; ++r) hb[r] = 0.f;
    const long tb = (long)b * TT;
#pragma unroll
    for (int c = 0; c < 8; ++c) {
        int j = tid + 256 * c;
        float sv = bf2f(hsr[j]);
        float sp = fmaxf(sv, 0.f) + log1pf(expf(-fabsf(sv)));
        float m = hmv[c] * inv;
        float hv = sp * (m > 0.f ? m : 0.f);
        h[base + j] = f2bf(hv);
#pragma unroll
        for (int r = 0; r < RS; ++r)
            hb[r] = fmaf(hv, bf2f(B2T[(long)r * MT + tb + j]), hb[r]);
    }
#pragma unroll
    for (int r = 0; r < RS; ++r)
#pragma unroll
        for (int off = 32; off; off >>= 1) hb[r] += __shfl_down(hb[r], off, 64);
    __shared__ float red[4][RS];
    if ((tid & 63) == 0)
#pragma unroll
        for (int r = 0; r < RS; ++r) red[tid >> 6][r] = hb[r];
    __syncthreads();
    if (tid < RS)
        hB[((long)b * TT + i) * RS + tid] =
            red[0][tid] + red[1][tid] + red[2][tid] + red[3][tid];
}

// ---------------------------------------------------------------------------
// vdT[b][d][t] = bf16(v[b][t][d] * d2[b*TT+t])
// ---------------------------------------------------------------------------
__global__ __launch_bounds__(256)
void vdt_kernel(const float* __restrict__ v, const float* __restrict__ d2,
                short* __restrict__ o)
{
    const int t0 = blockIdx.x * 32, d0 = blockIdx.y * 32, b = blockIdx.z;
    const int tx = threadIdx.x & 31, ty = threadIdx.x >> 5;
    __shared__ float tile[32][33];
    for (int s = 0; s < 32; s += 8) {
        int t = t0 + ty + s;
        tile[ty + s][tx] = v[((long)b * TT + t) * DD + d0 + tx] * d2[(long)b * TT + t];
    }
    __syncthreads();
    for (int s = 0; s < 32; s += 8) {
        int d = d0 + ty + s;
        o[((long)b * DD + d) * TT + t0 + tx] = f2bf(tile[tx][ty + s]);
    }
}

// A2tV[b][r][d] = sum_t A2T[r][b*TT+t] * v[b][t][d]
__global__ __launch_bounds__(256)
void a2tv_kernel(const float* __restrict__ v, const float* __restrict__ A2T,
                 float* __restrict__ o)
{
    const int d0 = blockIdx.x * 64, ks = blockIdx.y, b = blockIdx.z;
    const int dl = threadIdx.x & 63, tg = threadIdx.x >> 6;
    float acc[RS];
#pragma unroll
    for (int r = 0; r < RS; ++r) acc[r] = 0.f;
    for (int tt = 0; tt < 64; ++tt) {
        int t = ks * 256 + tg * 64 + tt;
        float vv = v[((long)b * TT + t) * DD + d0 + dl];
#pragma unroll
        for (int r = 0; r < RS; ++r)
            acc[r] = fmaf(A2T[(long)r * MT + b * TT + t], vv, acc[r]);
    }
    __shared__ float red[4][RS][64];
#pragma unroll
    for (int r = 0; r < RS; ++r) red[tg][r][dl] = acc[r];
    __syncthreads();
    for (int q = threadIdx.x; q < RS * 64; q += 256) {
        int r = q >> 6, d = q & 63;
        float s = red[0][r][d] + red[1][r][d] + red[2][r][d] + red[3][r][d];
        atomicAdd(&o[((long)b * RS + r) * DD + d0 + d], s);
    }
}

// cm = bf16((ctx + hB@A2tV) * mvo)
__global__ __launch_bounds__(256)
void fuse_out_kernel(const float* __restrict__ ctx, const float* __restrict__ mvo,
                     const float* __restrict__ hB, const float* __restrict__ A2tV,
                     short* __restrict__ cm)
{
    long i = (long)blockIdx.x * 256 + threadIdx.x;
    long row = i >> 10; int d = (int)(i & 1023); int b = (int)(row >> 11);
    float acc = ctx[i];
    const float* hb = hB + row * RS;
#pragma unroll
    for (int r = 0; r < RS; ++r)
        acc = fmaf(hb[r], A2tV[((long)b * RS + r) * DD + d], acc);
    cm[i] = f2bf(acc * mvo[i]);
}

// ---------------------------------------------------------------------------
extern "C" void kernel_launch(void* const* d_in, const int* in_sizes, int n_in,
                              void* d_out, int out_size, void* d_ws, size_t ws_size,
                              hipStream_t stream)
{
    (void)in_sizes; (void)n_in; (void)out_size; (void)ws_size;
    const float* x = (const float*)d_in[0];
    const float* W[27];
    for (int i = 1; i < 27; ++i) W[i] = (const float*)d_in[i];
    float* out = (float*)d_out;

    char* ws = (char*)d_ws;
    size_t off = 0;
    auto alloc = [&](size_t bytes) -> void* {
        void* p = ws + off; off += (bytes + 255) & ~(size_t)255; return p;
    };
    short* xb     = (short*)alloc((size_t)MT * DD * 2);          // -> VDT
    char*  wblock = (char*)alloc(0);                             // marker
    short* WcatT  = (short*)alloc((size_t)GLD * DD * 2);
    short* W2catT = (short*)alloc((size_t)8 * DD * 64 * 2);
    float* G      = (float*)alloc((size_t)MT * GLD * 4);
    short* Gb640  = (short*)alloc((size_t)MT * GLD * 2);         // wblock -> hs
    short* Wob    = (short*)alloc((size_t)DD * DD * 2);
    float* S0a    = (float*)alloc((size_t)MT * DD * 4);          // q
    float* S0b    = (float*)alloc((size_t)MT * DD * 4);          // qs -> cm
    float* S1     = (float*)alloc((size_t)MT * DD * 4);          // mvo
    float* S0v    = (float*)alloc((size_t)MT * DD * 4);          // v
    short* QGaug  = (short*)alloc((size_t)MT * KAUG * 2);
    short* QSGaug = (short*)alloc((size_t)MT * KAUG * 2);
    short* KBaug  = (short*)alloc((size_t)MT * KAUG * 2);
    short* KSBaug = (short*)alloc((size_t)MT * KAUG * 2);
    short* KBplain  = (short*)alloc((size_t)MT * DD * 2);        // -> h (first half)
    short* KSBplain = (short*)alloc((size_t)MT * DD * 2);        // -> h (second half)
    short* hm     = (short*)alloc((size_t)BB * TT * TT * 2);     // -> ctx (fp32)
    float* d1   = (float*)alloc((size_t)MT * 4);
    float* d1s  = (float*)alloc((size_t)MT * 4);
    float* d2   = (float*)alloc((size_t)MT * 4);
    float* B1T  = (float*)alloc((size_t)RS * MT * 4);
    float* B1sT = (float*)alloc((size_t)RS * MT * 4);
    short* B2T  = (short*)alloc((size_t)RS * MT * 2);
    float* A2T  = (float*)alloc((size_t)RS * MT * 4);
    float* C1   = (float*)alloc((size_t)BB * DD * RS * 4);       // | contiguous
    float* C1s  = (float*)alloc((size_t)BB * DD * RS * 4);       // | zero block
    float* A2tV = (float*)alloc((size_t)BB * RS * DD * 4);       // |
    short* C1b  = (short*)alloc((size_t)BB * DD * RS * 2);
    short* C1sb = (short*)alloc((size_t)BB * DD * RS * 2);
    float* hB   = (float*)alloc((size_t)MT * RS * 4);

    short* VDT = xb;               // xb dead after stage-1
    short* hs  = (short*)wblock;   // WcatT/W2catT/G/Gb640 dead after stage-2
    short* h   = KBplain;          // KBplain+KSBplain contiguous, dead after c1
    float* ctx = (float*)hm;       // hm dead after fuse_h3
    short* cm  = (short*)S0b;      // S0b dead after stage-2 launch B

    const long n4 = (long)MT * DD / 4;

    // --- input/weight conversion ---
    f2bf_vec_kernel<<<n4 / 256, 256, 0, stream>>>(x, xb, n4);
    ConcatArgs ca;
    {
        const int w1idx[8] = {1, 3, 5, 7, 9, 11, 13, 15};
        for (int s = 0; s < 8; ++s) { ca.p[s] = W[w1idx[s]]; ca.col0[s] = s * 64; ca.wid[s] = 64; }
        const int didx[9] = {18, 19, 20, 21, 22, 23, 24, 25, 26};
        const int dcol[9] = {512, 513, 529, 545, 546, 562, 578, 579, 595};
        const int dwid[9] = {1, 16, 16, 1, 16, 16, 1, 16, 16};
        for (int s = 0; s < 9; ++s) { ca.p[8 + s] = W[didx[s]]; ca.col0[8 + s] = dcol[s]; ca.wid[8 + s] = dwid[s]; }
    }
    concat_w1_kernel<<<GLD, 256, 0, stream>>>(ca, WcatT);
    Ptrs8 p8;
    {
        const int w2idx[8] = {2, 4, 6, 8, 10, 12, 14, 16};
        for (int s = 0; s < 8; ++s) p8.p[s] = W[w2idx[s]];
    }
    concat_w2_kernel<<<dim3(DD / 64, 8), 256, 0, stream>>>(p8, W2catT);
    f2bf_vec_kernel<<<((long)DD * DD / 4) / 256, 256, 0, stream>>>(W[17], Wob, (long)DD * DD / 4);

    // --- stage-1: G = xb @ WcatT^T ---
    gemm_nt<0><<<dim3(GLD / 128, MT / 128, 1), 256, 0, stream>>>(
        xb, WcatT, G, DD, DD, DD, GLD, 0, 0, 0);
    f2bf_vec_kernel<<<((long)MT * GLD / 4) / 256, 256, 0, stream>>>(G, Gb640, (long)MT * GLD / 4);
    genprep_kernel<<<MT / 256, 256, 0, stream>>>(G, d1, d1s, d2, B1T, B1sT, B2T, A2T,
                                                 QGaug, QSGaug, KBaug, KSBaug);
    zero_kernel<<<(3 * BB * DD * RS + 255) / 256, 256, 0, stream>>>(C1, (long)3 * BB * DD * RS);

    // --- stage-2 launch A (independent slices) ---
    S2Args a;
    a.sl[0] = {0, 0, 0, S0a, nullptr, nullptr, nullptr, nullptr};            // q
    a.sl[1] = {3, 0, 0, S0b, nullptr, nullptr, nullptr, nullptr};            // qs
    a.sl[2] = {2, 3, KAUG, nullptr, KBaug, KBplain, nullptr, d1};            // k (dual)
    a.sl[3] = {5, 3, KAUG, nullptr, KSBaug, KSBplain, nullptr, d1s};         // ks (dual)
    a.sl[4] = {6, 0, 0, S0v, nullptr, nullptr, nullptr, nullptr};            // v
    a.sl[5] = {7, 0, 0, S1, nullptr, nullptr, nullptr, nullptr};             // mvo
    stage2_kernel<<<dim3(DD / 128, MT / 128, 6), 256, 0, stream>>>(Gb640, W2catT, a);

    // --- stage-2 launch B (gated by q/qs) ---
    S2Args bargs;
    bargs.sl[0] = {1, 2, KAUG, nullptr, QGaug, nullptr, S0a, nullptr};       // mg * q
    bargs.sl[1] = {4, 2, KAUG, nullptr, QSGaug, nullptr, S0b, nullptr};      // mgs * qs
    stage2_kernel<<<dim3(DD / 128, MT / 128, 2), 256, 0, stream>>>(Gb640, W2catT, bargs);

    // --- v-derived operands ---
    vdt_kernel<<<dim3(TT / 32, DD / 32, BB), 256, 0, stream>>>(S0v, d2, VDT);
    a2tv_kernel<<<dim3(DD / 64, 8, BB), 256, 0, stream>>>(S0v, A2T, A2tV);

    // --- C1 = kb^T @ B1 (and scale path), then zB into aug cols ---
    c1_kernel<<<dim3(DD / 64, TT / 256, BB), 256, 0, stream>>>(KBplain, B1T, C1);
    c1_kernel<<<dim3(DD / 64, TT / 256, BB), 256, 0, stream>>>(KSBplain, B1sT, C1s);
    c1conv_kernel<<<(BB * DD * RS) / 256, 256, 0, stream>>>(C1, C1s, C1b, C1sb);
    zb_kernel<<<MT, 256, 0, stream>>>(QGaug, C1b);
    zb_kernel<<<MT, 256, 0, stream>>>(QSGaug, C1sb);

    // --- hm/hs = aug @ aug^T (one launch, 4 tiles-z) ---
    hmhs_kernel<<<dim3(TT / 128, TT / 128, 4), 256, 0, stream>>>(
        QGaug, QSGaug, KBaug, KSBaug, hm, hs);

    // --- fuse: norm + HyperGLU -> h, hB ---
    fuse_h3_kernel<<<dim3(TT, BB), 256, 0, stream>>>(hm, hs, B2T, h, hB);

    // --- context = h @ VDT^T ---
    gemm_nt<0><<<dim3(DD / 128, TT / 128, BB), 256, 0, stream>>>(
        h, VDT, ctx, TT, TT, TT, DD, (long)TT * TT, (long)DD * TT, (long)TT * DD);

    // --- cm = bf16((ctx + hB@A2tV) * mvo) ---
    fuse_out_kernel<<<((long)MT * DD) / 256, 256, 0, stream>>>(ctx, S1, hB, A2tV, cm);

    // --- out = cm @ Wo^T ---
    gemm_nt<0><<<dim3(DD / 128, MT / 128, 1), 256, 0, stream>>>(
        cm, Wob, out, DD, DD, DD, DD, 0, 0, 0);
}

// Round 4
// 406.777 us; speedup vs baseline: 11.0602x; 1.1049x over previous
//
#include <hip/hip_runtime.h>
#include <math.h>

#define BB 2
#define TT 2048
#define DD 1024
#define RS 16
#define MT (BB*TT)      // 4096 flattened rows
#define GLD 640         // stage-1 concat output width (611 used, padded)
#define KAUG 1056       // 1024 + 16 (zB/A1) + 16 zero pad; multiple of 32

typedef __attribute__((ext_vector_type(8))) short s16x8;
typedef __attribute__((ext_vector_type(4))) float f32x4;

__device__ __forceinline__ short f2bf(float f) {
    union { float f; unsigned u; } v; v.f = f;
    unsigned r = (v.u + 0x7fffu + ((v.u >> 16) & 1u)) >> 16;
    return (short)r;
}
__device__ __forceinline__ float bf2f(short s) {
    union { unsigned u; float f; } v; v.u = ((unsigned)(unsigned short)s) << 16;
    return v.f;
}

__device__ __forceinline__ void gload16(const void* g, void* l) {
    __builtin_amdgcn_global_load_lds((const __attribute__((address_space(1))) void*)g,
                                     (__attribute__((address_space(3))) void*)l, 16, 0, 0);
}

// XCD-aware block swizzle (all grids are multiples of 8 -> bijective).
__device__ __forceinline__ void xcd_swz(int& bx, int& by, int& bz)
{
    const int gx = gridDim.x, gy = gridDim.y;
    const int n = gx * gy * (int)gridDim.z;
    int flat = (bz * gy + by) * gx + bx;
    const int cpx = n >> 3;
    flat = (flat & 7) * cpx + (flat >> 3);
    bx = flat % gx; by = (flat / gx) % gy; bz = flat / (gx * gy);
}

// ---------------------------------------------------------------------------
// Shared 128x128 NT tile core: acc = A[bi:bi+128, :K] @ Bt[bj:bj+128, :K]^T
// 4 waves (2x2), 16x16x32 bf16 MFMA, BK=32, global_load_lds staging.
// Bank-conflict fix: granule XOR-swizzle (rule #21: linear LDS dest +
// inverse-swizzled GLOBAL source + swizzled read). g' = g ^ ((row>>1)&3)
// spreads 16 rows across all eight 16B slots per 128B bank cycle.
// ---------------------------------------------------------------------------
__device__ __forceinline__ void gemm_core128(const short* __restrict__ A,
                                             const short* __restrict__ Bt,
                                             int K, int lda, int ldb,
                                             int bi, int bj, short* smem,
                                             f32x4 (&acc)[4][4])
{
    const int tid = threadIdx.x;
    const int wv = tid >> 6, lane = tid & 63;
    const int wr = (wv >> 1) * 64, wc = (wv & 1) * 64;
    short* Asm = smem;
    short* Bsm = smem + 4096;

#pragma unroll
    for (int m = 0; m < 4; ++m)
#pragma unroll
        for (int n = 0; n < 4; ++n) acc[m][n] = (f32x4){0.f, 0.f, 0.f, 0.f};

    const int srow = wv * 16 + (lane >> 2);               // staging row (+ p*64)
    const int sg   = ((lane & 3) ^ ((srow >> 1) & 3)) * 8; // swizzled src granule
    const int frow = lane & 15;
    const int gidx = lane >> 4;                            // fragment granule
    const int rsw  = (frow >> 1) & 3;
    const int koff = (gidx ^ rsw) * 8;                     // swizzled read offset

    for (int k0 = 0; k0 < K; k0 += 32) {
#pragma unroll
        for (int p = 0; p < 2; ++p) {
            gload16(A  + (long)(bi + p*64 + srow) * lda + k0 + sg, Asm + p*2048 + wv*512);
            gload16(Bt + (long)(bj + p*64 + srow) * ldb + k0 + sg, Bsm + p*2048 + wv*512);
        }
        __syncthreads();
        s16x8 af[4], bfr[4];
#pragma unroll
        for (int m = 0; m < 4; ++m)
            af[m] = *(const s16x8*)&Asm[(wr + m*16 + frow) * 32 + koff];
#pragma unroll
        for (int n = 0; n < 4; ++n)
            bfr[n] = *(const s16x8*)&Bsm[(wc + n*16 + frow) * 32 + koff];
#pragma unroll
        for (int m = 0; m < 4; ++m)
#pragma unroll
            for (int n = 0; n < 4; ++n)
                acc[m][n] = __builtin_amdgcn_mfma_f32_16x16x32_bf16(af[m], bfr[n], acc[m][n], 0, 0, 0);
        __syncthreads();
    }
}

// Generic batched NT GEMM; STORE 0 = fp32 out, 1 = bf16 out.
template<int STORE>
__global__ __launch_bounds__(256)
void gemm_nt(const short* __restrict__ A, const short* __restrict__ Bt,
             void* __restrict__ Cv, int K, int lda, int ldb, int ldc,
             long sA, long sB, long sC)
{
    int bx = blockIdx.x, by = blockIdx.y, bz = blockIdx.z;
    xcd_swz(bx, by, bz);
    const short* Ab = A  + (long)bz * sA;
    const short* Bb = Bt + (long)bz * sB;
    const int bi = by * 128, bj = bx * 128;
    __shared__ __align__(16) short smem[8192];
    f32x4 acc[4][4];
    gemm_core128(Ab, Bb, K, lda, ldb, bi, bj, smem, acc);

    const int lane = threadIdx.x & 63, wv = threadIdx.x >> 6;
    const int wr = (wv >> 1) * 64, wc = (wv & 1) * 64;
    const int col0 = lane & 15, row0 = (lane >> 4) * 4;
#pragma unroll
    for (int m = 0; m < 4; ++m)
#pragma unroll
        for (int n = 0; n < 4; ++n)
#pragma unroll
            for (int r = 0; r < 4; ++r) {
                int i = bi + wr + m*16 + row0 + r;
                int j = bj + wc + n*16 + col0;
                if (STORE == 0)
                    ((float*)Cv + (long)bz * sC)[(long)i * ldc + j] = acc[m][n][r];
                else
                    ((short*)Cv + (long)bz * sC)[(long)i * ldc + j] = f2bf(acc[m][n][r]);
            }
}

// Stage-1: G[MT][GLD] fp32 + Gb512[MT][512] bf16 dual store.
__global__ __launch_bounds__(256)
void gemm_s1(const short* __restrict__ xb, const short* __restrict__ WcatT,
             float* __restrict__ G, short* __restrict__ Gb512)
{
    int bx = blockIdx.x, by = blockIdx.y, bz = blockIdx.z;
    xcd_swz(bx, by, bz);
    const int bi = by * 128, bj = bx * 128;
    __shared__ __align__(16) short smem[8192];
    f32x4 acc[4][4];
    gemm_core128(xb, WcatT, DD, DD, DD, bi, bj, smem, acc);

    const int lane = threadIdx.x & 63, wv = threadIdx.x >> 6;
    const int wr = (wv >> 1) * 64, wc = (wv & 1) * 64;
    const int col0 = lane & 15, row0 = (lane >> 4) * 4;
#pragma unroll
    for (int m = 0; m < 4; ++m)
#pragma unroll
        for (int n = 0; n < 4; ++n)
#pragma unroll
            for (int r = 0; r < 4; ++r) {
                int i = bi + wr + m*16 + row0 + r;
                int j = bj + wc + n*16 + col0;
                float val = acc[m][n][r];
                G[(long)i * GLD + j] = val;
                if (j < 512) Gb512[(long)i * 512 + j] = f2bf(val);
            }
}

// hm/hs producer: blockIdx.z selects (batch, gate-vs-scale); bf16 out.
__global__ __launch_bounds__(256)
void hmhs_kernel(const short* __restrict__ QGaug, const short* __restrict__ QSGaug,
                 const short* __restrict__ KBaug, const short* __restrict__ KSBaug,
                 short* __restrict__ hm, short* __restrict__ hs)
{
    int bx = blockIdx.x, by = blockIdx.y, bz = blockIdx.z;
    xcd_swz(bx, by, bz);
    const int b = bz & 1, which = bz >> 1;
    const short* A  = (which ? QSGaug : QGaug) + (long)b * TT * KAUG;
    const short* Bt = (which ? KSBaug : KBaug) + (long)b * TT * KAUG;
    short* C = (which ? hs : hm) + (long)b * TT * TT;
    const int bi = by * 128, bj = bx * 128;
    __shared__ __align__(16) short smem[8192];
    f32x4 acc[4][4];
    gemm_core128(A, Bt, KAUG, KAUG, KAUG, bi, bj, smem, acc);

    const int lane = threadIdx.x & 63, wv = threadIdx.x >> 6;
    const int wr = (wv >> 1) * 64, wc = (wv & 1) * 64;
    const int col0 = lane & 15, row0 = (lane >> 4) * 4;
#pragma unroll
    for (int m = 0; m < 4; ++m)
#pragma unroll
        for (int n = 0; n < 4; ++n)
#pragma unroll
            for (int r = 0; r < 4; ++r) {
                int i = bi + wr + m*16 + row0 + r;
                int j = bj + wc + n*16 + col0;
                C[(long)i * TT + j] = f2bf(acc[m][n][r]);
            }
}

// ---------------------------------------------------------------------------
// Stage-2 multi-slice GEMM (K=64 per pass).
// mode 0 (GATE): two passes (sa,sb); out bf16(acc*acc2) at ldc KAUG.
// mode 1 (DUAL): outS2 plain bf16 ldc DD; outS bf16(acc*rs[i]) ldc KAUG.
// mode 2 (F32):  outF fp32 ldc DD.
// ---------------------------------------------------------------------------
struct S2S { int mode, sa, sb; short* outS; short* outS2; float* outF; const float* rs; };
struct S2A { S2S sl[6]; };

__global__ __launch_bounds__(256)
void stage2_kernel(const short* __restrict__ Gb, const short* __restrict__ W2,
                   S2A args)
{
    int bx = blockIdx.x, by = blockIdx.y, bz = blockIdx.z;
    xcd_swz(bx, by, bz);
    const S2S sl = args.sl[bz];
    const int bi = by * 128, bj = bx * 128;
    __shared__ __align__(16) short smem[8192];
    f32x4 acc[4][4];
    gemm_core128(Gb + sl.sa * 64, W2 + (long)sl.sa * DD * 64, 64, 512, 64, bi, bj, smem, acc);
    f32x4 acc2[4][4];
    if (sl.mode == 0)
        gemm_core128(Gb + sl.sb * 64, W2 + (long)sl.sb * DD * 64, 64, 512, 64, bi, bj, smem, acc2);

    const int lane = threadIdx.x & 63, wv = threadIdx.x >> 6;
    const int wr = (wv >> 1) * 64, wc = (wv & 1) * 64;
    const int col0 = lane & 15, row0 = (lane >> 4) * 4;
#pragma unroll
    for (int m = 0; m < 4; ++m)
#pragma unroll
        for (int n = 0; n < 4; ++n)
#pragma unroll
            for (int r = 0; r < 4; ++r) {
                int i = bi + wr + m*16 + row0 + r;
                int j = bj + wc + n*16 + col0;
                float val = acc[m][n][r];
                if (sl.mode == 0) {
                    sl.outS[(long)i * KAUG + j] = f2bf(val * acc2[m][n][r]);
                } else if (sl.mode == 1) {
                    sl.outS2[(long)i * DD + j] = f2bf(val);
                    sl.outS[(long)i * KAUG + j] = f2bf(val * sl.rs[i]);
                } else {
                    sl.outF[(long)i * DD + j] = val;
                }
            }
}

// ---------------------------------------------------------------------------
// Context GEMM with fused epilogue: cm = bf16((h@VDT^T + hB@A2tV) * mvo)
// ---------------------------------------------------------------------------
__global__ __launch_bounds__(256)
void ctx_kernel(const short* __restrict__ h, const short* __restrict__ VDT,
                const float* __restrict__ mvo, const float* __restrict__ hB,
                const float* __restrict__ A2tV, short* __restrict__ cm)
{
    int bx = blockIdx.x, by = blockIdx.y, bz = blockIdx.z;
    xcd_swz(bx, by, bz);
    const int b = bz;
    const int bi = by * 128, bj = bx * 128;
    __shared__ __align__(16) short smem[8192];
    f32x4 acc[4][4];
    gemm_core128(h + (long)b * TT * TT, VDT + (long)b * DD * TT, TT, TT, TT, bi, bj, smem, acc);

    const int lane = threadIdx.x & 63, wv = threadIdx.x >> 6;
    const int wr = (wv >> 1) * 64, wc = (wv & 1) * 64;
    const int col0 = lane & 15, row0 = (lane >> 4) * 4;
    const float* a2 = A2tV + (long)b * RS * DD;

    // rank-16 correction, fp32 (r16 outermost keeps registers flat)
#pragma unroll
    for (int r16 = 0; r16 < RS; ++r16) {
        float a2v[4];
#pragma unroll
        for (int n = 0; n < 4; ++n)
            a2v[n] = a2[(long)r16 * DD + bj + wc + n*16 + col0];
#pragma unroll
        for (int m = 0; m < 4; ++m)
#pragma unroll
            for (int r = 0; r < 4; ++r) {
                long gi = (long)b * TT + bi + wr + m*16 + row0 + r;
                float hb = hB[gi * RS + r16];
#pragma unroll
                for (int n = 0; n < 4; ++n)
                    acc[m][n][r] = fmaf(hb, a2v[n], acc[m][n][r]);
            }
    }
#pragma unroll
    for (int m = 0; m < 4; ++m)
#pragma unroll
        for (int n = 0; n < 4; ++n)
#pragma unroll
            for (int r = 0; r < 4; ++r) {
                long gi = (long)b * TT + bi + wr + m*16 + row0 + r;
                int j = bj + wc + n*16 + col0;
                cm[gi * DD + j] = f2bf(acc[m][n][r] * mvo[gi * DD + j]);
            }
}

// ---------------------------------------------------------------------------
// Weight prep
// ---------------------------------------------------------------------------
struct ConcatArgs { const float* p[17]; int col0[17]; int wid[17]; };

__global__ __launch_bounds__(256)
void concat_w1_kernel(ConcatArgs a, short* __restrict__ WcatT)
{
    const int n = blockIdx.x;
    int s = -1, c = 0;
    for (int i = 0; i < 17; ++i)
        if (n >= a.col0[i] && n < a.col0[i] + a.wid[i]) { s = i; c = n - a.col0[i]; }
    for (int k = threadIdx.x; k < DD; k += 256)
        WcatT[(long)n * DD + k] = (s < 0) ? (short)0 : f2bf(a.p[s][(long)k * a.wid[s] + c]);
}

struct Ptrs8 { const float* p[8]; };

__global__ __launch_bounds__(256)
void concat_w2_kernel(Ptrs8 a, short* __restrict__ W2catT)
{
    const int s = blockIdx.y, n0 = blockIdx.x * 64;
    const int tx = threadIdx.x & 63, ty = threadIdx.x >> 6;
    __shared__ float t[64][65];
    const float* W2 = a.p[s];
    for (int kk = ty; kk < 64; kk += 4) t[kk][tx] = W2[(long)kk * DD + n0 + tx];
    __syncthreads();
    for (int n = ty; n < 64; n += 4)
        W2catT[((long)s * DD + n0 + n) * 64 + tx] = f2bf(t[tx][n]);
}

__global__ __launch_bounds__(256)
void f2bf_vec_kernel(const float* __restrict__ in, short* __restrict__ o, long n4)
{
    long i = (long)blockIdx.x * 256 + threadIdx.x;
    if (i < n4) {
        float4 v = ((const float4*)in)[i];
        short4 r; r.x = f2bf(v.x); r.y = f2bf(v.y); r.z = f2bf(v.z); r.w = f2bf(v.w);
        ((short4*)o)[i] = r;
    }
}

// ---------------------------------------------------------------------------
// genprep: SoA-extract DPLR generators from G + fill aug constants/pads.
// ---------------------------------------------------------------------------
__global__ __launch_bounds__(256)
void genprep_kernel(const float* __restrict__ G, float* __restrict__ d1,
                    float* __restrict__ d1s, float* __restrict__ d2,
                    float* __restrict__ B1T, float* __restrict__ B1sT,
                    short* __restrict__ B2T, float* __restrict__ A2T,
                    short* __restrict__ QGaug, short* __restrict__ QSGaug,
                    short* __restrict__ KBaug, short* __restrict__ KSBaug)
{
    const int i = blockIdx.x * 256 + threadIdx.x;
    const float* g = G + (long)i * GLD;
    d1[i]  = g[512];
    d1s[i] = g[545];
    d2[i]  = g[578];
#pragma unroll
    for (int r = 0; r < RS; ++r) {
        KBaug [(long)i * KAUG + 1024 + r] = f2bf(g[513 + r]);
        KSBaug[(long)i * KAUG + 1024 + r] = f2bf(g[546 + r]);
        B1T [(long)r * MT + i] = g[529 + r];
        B1sT[(long)r * MT + i] = g[562 + r];
        A2T [(long)r * MT + i] = g[579 + r];
        B2T [(long)r * MT + i] = f2bf(g[595 + r]);
        KBaug [(long)i * KAUG + 1040 + r] = 0;
        KSBaug[(long)i * KAUG + 1040 + r] = 0;
        QGaug [(long)i * KAUG + 1040 + r] = 0;
        QSBFIX:
        ;
    }
#pragma unroll
    for (int r = 0; r < RS; ++r)
        QSGaug[(long)i * KAUG + 1040 + r] = 0;
}

__global__ __launch_bounds__(256)
void zero_kernel(float* __restrict__ p, long n)
{
    long i = (long)blockIdx.x * 256 + threadIdx.x;
    if (i < n) p[i] = 0.f;
}

// ---------------------------------------------------------------------------
// C1[b][d][r] = sum_t kb[b][t][d] * B1T[r][b*TT+t]   (atomic k-split)
// ---------------------------------------------------------------------------
__global__ __launch_bounds__(256)
void c1_kernel(const short* __restrict__ kb, const float* __restrict__ BT,
               float* __restrict__ C1)
{
    const int d0 = blockIdx.x * 64, t0 = blockIdx.y * 256, b = blockIdx.z;
    const int dl = threadIdx.x & 63, tg = threadIdx.x >> 6;
    float acc[RS];
#pragma unroll
    for (int r = 0; r < RS; ++r) acc[r] = 0.f;
    for (int tt = 0; tt < 64; ++tt) {
        int t = t0 + tg * 64 + tt;
        float kv = bf2f(kb[((long)b * TT + t) * DD + d0 + dl]);
#pragma unroll
        for (int r = 0; r < RS; ++r)
            acc[r] = fmaf(kv, BT[(long)r * MT + b * TT + t], acc[r]);
    }
    __shared__ float red[4][RS][64];
#pragma unroll
    for (int r = 0; r < RS; ++r) red[tg][r][dl] = acc[r];
    __syncthreads();
    for (int q = threadIdx.x; q < RS * 64; q += 256) {
        int r = q >> 6, d = q & 63;
        float s = red[0][r][d] + red[1][r][d] + red[2][r][d] + red[3][r][d];
        atomicAdd(&C1[((long)b * DD + d0 + d) * RS + r], s);
    }
}

__global__ __launch_bounds__(256)
void c1conv_kernel(const float* __restrict__ C1, const float* __restrict__ C1s,
                   short* __restrict__ C1b, short* __restrict__ C1sb)
{
    int i = blockIdx.x * 256 + threadIdx.x;   // BB*DD*RS = 32768
    C1b[i]  = f2bf(C1[i]);
    C1sb[i] = f2bf(C1s[i]);
}

// zB[i][:] = qg[i][:1024] @ C1b[b]  -> written into aug cols 1024..1039
__global__ __launch_bounds__(256)
void zb_kernel(short* __restrict__ aug, const short* __restrict__ C1b)
{
    const int gi = blockIdx.x, b = gi >> 11, tid = threadIdx.x;
    const short* qrow = aug + (long)gi * KAUG;
    const short* c1 = C1b + (long)b * DD * RS;
    float acc[RS];
#pragma unroll
    for (int r = 0; r < RS; ++r) acc[r] = 0.f;
#pragma unroll
    for (int c = 0; c < 4; ++c) {
        int d = tid + 256 * c;
        float q = bf2f(qrow[d]);
        const short* cr = c1 + (long)d * RS;
#pragma unroll
        for (int r = 0; r < RS; ++r) acc[r] = fmaf(q, bf2f(cr[r]), acc[r]);
    }
#pragma unroll
    for (int r = 0; r < RS; ++r)
#pragma unroll
        for (int off = 32; off; off >>= 1) acc[r] += __shfl_down(acc[r], off, 64);
    __shared__ float red[4][RS];
    if ((tid & 63) == 0)
#pragma unroll
        for (int r = 0; r < RS; ++r) red[tid >> 6][r] = acc[r];
    __syncthreads();
    if (tid < RS)
        aug[(long)gi * KAUG + 1024 + tid] =
            f2bf(red[0][tid] + red[1][tid] + red[2][tid] + red[3][tid]);
}

// ---------------------------------------------------------------------------
// fuse: L2-norm(hm row) + softplus(hs)*relu -> h bf16; hB = h row @ B2 (SoA)
// ---------------------------------------------------------------------------
__global__ __launch_bounds__(256)
void fuse_h3_kernel(const short* __restrict__ hm, const short* __restrict__ hs,
                    const short* __restrict__ B2T, short* __restrict__ h,
                    float* __restrict__ hB)
{
    const int i = blockIdx.x, b = blockIdx.y, tid = threadIdx.x;
    const long base = ((long)b * TT + i) * TT;
    const short* hmr = hm + base;
    const short* hsr = hs + base;

    float hmv[8]; float ss = 0.f;
#pragma unroll
    for (int c = 0; c < 8; ++c) {
        float v = bf2f(hmr[tid + 256 * c]);
        hmv[c] = v; ss = fmaf(v, v, ss);
    }
#pragma unroll
    for (int off = 32; off; off >>= 1) ss += __shfl_down(ss, off, 64);
    __shared__ float w4[4];
    if ((tid & 63) == 0) w4[tid >> 6] = ss;
    __syncthreads();
    const float inv = 1.f / (sqrtf(w4[0] + w4[1] + w4[2] + w4[3]) + 1e-8f);

    float hb[RS];
#pragma unroll
    for (int r = 0; r < RS; ++r) hb[r] = 0.f;
    const long tb = (long)b * TT;
#pragma unroll
    for (int c = 0; c < 8; ++c) {
        int j = tid + 256 * c;
        float sv = bf2f(hsr[j]);
        float sp = fmaxf(sv, 0.f) + log1pf(expf(-fabsf(sv)));
        float m = hmv[c] * inv;
        float hv = sp * (m > 0.f ? m : 0.f);
        h[base + j] = f2bf(hv);
#pragma unroll
        for (int r = 0; r < RS; ++r)
            hb[r] = fmaf(hv, bf2f(B2T[(long)r * MT + tb + j]), hb[r]);
    }
#pragma unroll
    for (int r = 0; r < RS; ++r)
#pragma unroll
        for (int off = 32; off; off >>= 1) hb[r] += __shfl_down(hb[r], off, 64);
    __shared__ float red[4][RS];
    if ((tid & 63) == 0)
#pragma unroll
        for (int r = 0; r < RS; ++r) red[tid >> 6][r] = hb[r];
    __syncthreads();
    if (tid < RS)
        hB[((long)b * TT + i) * RS + tid] =
            red[0][tid] + red[1][tid] + red[2][tid] + red[3][tid];
}

// ---------------------------------------------------------------------------
// vdT[b][d][t] = bf16(v[b][t][d] * d2[b*TT+t])
// ---------------------------------------------------------------------------
__global__ __launch_bounds__(256)
void vdt_kernel(const float* __restrict__ v, const float* __restrict__ d2,
                short* __restrict__ o)
{
    const int t0 = blockIdx.x * 32, d0 = blockIdx.y * 32, b = blockIdx.z;
    const int tx = threadIdx.x & 31, ty = threadIdx.x >> 5;
    __shared__ float tile[32][33];
    for (int s = 0; s < 32; s += 8) {
        int t = t0 + ty + s;
        tile[ty + s][tx] = v[((long)b * TT + t) * DD + d0 + tx] * d2[(long)b * TT + t];
    }
    __syncthreads();
    for (int s = 0; s < 32; s += 8) {
        int d = d0 + ty + s;
        o[((long)b * DD + d) * TT + t0 + tx] = f2bf(tile[tx][ty + s]);
    }
}

// A2tV[b][r][d] = sum_t A2T[r][b*TT+t] * v[b][t][d]
__global__ __launch_bounds__(256)
void a2tv_kernel(const float* __restrict__ v, const float* __restrict__ A2T,
                 float* __restrict__ o)
{
    const int d0 = blockIdx.x * 64, ks = blockIdx.y, b = blockIdx.z;
    const int dl = threadIdx.x & 63, tg = threadIdx.x >> 6;
    float acc[RS];
#pragma unroll
    for (int r = 0; r < RS; ++r) acc[r] = 0.f;
    for (int tt = 0; tt < 64; ++tt) {
        int t = ks * 256 + tg * 64 + tt;
        float vv = v[((long)b * TT + t) * DD + d0 + dl];
#pragma unroll
        for (int r = 0; r < RS; ++r)
            acc[r] = fmaf(A2T[(long)r * MT + b * TT + t], vv, acc[r]);
    }
    __shared__ float red[4][RS][64];
#pragma unroll
    for (int r = 0; r < RS; ++r) red[tg][r][dl] = acc[r];
    __syncthreads();
    for (int q = threadIdx.x; q < RS * 64; q += 256) {
        int r = q >> 6, d = q & 63;
        float s = red[0][r][d] + red[1][r][d] + red[2][r][d] + red[3][r][d];
        atomicAdd(&o[((long)b * RS + r) * DD + d0 + d], s);
    }
}

// ---------------------------------------------------------------------------
extern "C" void kernel_launch(void* const* d_in, const int* in_sizes, int n_in,
                              void* d_out, int out_size, void* d_ws, size_t ws_size,
                              hipStream_t stream)
{
    (void)in_sizes; (void)n_in; (void)out_size; (void)ws_size;
    const float* x = (const float*)d_in[0];
    const float* W[27];
    for (int i = 1; i < 27; ++i) W[i] = (const float*)d_in[i];
    float* out = (float*)d_out;

    char* ws = (char*)d_ws;
    size_t off = 0;
    auto alloc = [&](size_t bytes) -> void* {
        void* p = ws + off; off += (bytes + 255) & ~(size_t)255; return p;
    };
    short* xb     = (short*)alloc((size_t)MT * DD * 2);          // -> VDT
    char*  wblock = (char*)alloc(0);                             // marker
    short* WcatT  = (short*)alloc((size_t)GLD * DD * 2);
    short* W2catT = (short*)alloc((size_t)8 * DD * 64 * 2);
    float* G      = (float*)alloc((size_t)MT * GLD * 4);
    short* Gb512  = (short*)alloc((size_t)MT * 512 * 2);         // wblock span -> hs
    short* Wob    = (short*)alloc((size_t)DD * DD * 2);
    float* S1     = (float*)alloc((size_t)MT * DD * 4);          // mvo fp32
    float* S0v    = (float*)alloc((size_t)MT * DD * 4);          // v fp32
    short* QGaug  = (short*)alloc((size_t)MT * KAUG * 2);        // -> cm
    short* QSGaug = (short*)alloc((size_t)MT * KAUG * 2);
    short* KBaug  = (short*)alloc((size_t)MT * KAUG * 2);
    short* KSBaug = (short*)alloc((size_t)MT * KAUG * 2);
    short* KBplain  = (short*)alloc((size_t)MT * DD * 2);        // -> h (first half)
    short* KSBplain = (short*)alloc((size_t)MT * DD * 2);        // -> h (second half)
    short* hm     = (short*)alloc((size_t)BB * TT * TT * 2);
    float* d1   = (float*)alloc((size_t)MT * 4);
    float* d1s  = (float*)alloc((size_t)MT * 4);
    float* d2   = (float*)alloc((size_t)MT * 4);
    float* B1T  = (float*)alloc((size_t)RS * MT * 4);
    float* B1sT = (float*)alloc((size_t)RS * MT * 4);
    short* B2T  = (short*)alloc((size_t)RS * MT * 2);
    float* A2T  = (float*)alloc((size_t)RS * MT * 4);
    float* C1   = (float*)alloc((size_t)BB * DD * RS * 4);       // | contiguous
    float* C1s  = (float*)alloc((size_t)BB * DD * RS * 4);       // | zero block
    float* A2tV = (float*)alloc((size_t)BB * RS * DD * 4);       // |
    short* C1b  = (short*)alloc((size_t)BB * DD * RS * 2);
    short* C1sb = (short*)alloc((size_t)BB * DD * RS * 2);
    float* hB   = (float*)alloc((size_t)MT * RS * 4);

    short* VDT = xb;               // xb dead after stage-1
    short* hs  = (short*)wblock;   // WcatT/W2catT/G/Gb512 span (17.0MB >= 16.8MB)
    short* h   = KBplain;          // KBplain+KSBplain contiguous, dead after c1
    short* cm  = QGaug;            // QGaug dead after hmhs

    const long n4 = (long)MT * DD / 4;

    // --- input/weight conversion ---
    f2bf_vec_kernel<<<n4 / 256, 256, 0, stream>>>(x, xb, n4);
    ConcatArgs ca;
    {
        const int w1idx[8] = {1, 3, 5, 7, 9, 11, 13, 15};
        for (int s = 0; s < 8; ++s) { ca.p[s] = W[w1idx[s]]; ca.col0[s] = s * 64; ca.wid[s] = 64; }
        const int didx[9] = {18, 19, 20, 21, 22, 23, 24, 25, 26};
        const int dcol[9] = {512, 513, 529, 545, 546, 562, 578, 579, 595};
        const int dwid[9] = {1, 16, 16, 1, 16, 16, 1, 16, 16};
        for (int s = 0; s < 9; ++s) { ca.p[8 + s] = W[didx[s]]; ca.col0[8 + s] = dcol[s]; ca.wid[8 + s] = dwid[s]; }
    }
    concat_w1_kernel<<<GLD, 256, 0, stream>>>(ca, WcatT);
    Ptrs8 p8;
    {
        const int w2idx[8] = {2, 4, 6, 8, 10, 12, 14, 16};
        for (int s = 0; s < 8; ++s) p8.p[s] = W[w2idx[s]];
    }
    concat_w2_kernel<<<dim3(DD / 64, 8), 256, 0, stream>>>(p8, W2catT);
    f2bf_vec_kernel<<<((long)DD * DD / 4) / 256, 256, 0, stream>>>(W[17], Wob, (long)DD * DD / 4);

    // --- stage-1: G fp32 + Gb512 bf16 (dual store) ---
    gemm_s1<<<dim3(GLD / 128, MT / 128, 1), 256, 0, stream>>>(xb, WcatT, G, Gb512);
    genprep_kernel<<<MT / 256, 256, 0, stream>>>(G, d1, d1s, d2, B1T, B1sT, B2T, A2T,
                                                 QGaug, QSGaug, KBaug, KSBaug);
    zero_kernel<<<(3 * BB * DD * RS + 255) / 256, 256, 0, stream>>>(C1, (long)3 * BB * DD * RS);

    // --- stage-2: one launch, 6 slices (gate products fused) ---
    S2A a;
    a.sl[0] = {0, 0, 1, QGaug,  nullptr,  nullptr, nullptr};   // q*mg
    a.sl[1] = {0, 3, 4, QSGaug, nullptr,  nullptr, nullptr};   // qs*mgs
    a.sl[2] = {1, 2, 0, KBaug,  KBplain,  nullptr, d1};        // k dual
    a.sl[3] = {1, 5, 0, KSBaug, KSBplain, nullptr, d1s};       // ks dual
    a.sl[4] = {2, 6, 0, nullptr, nullptr, S0v,     nullptr};   // v fp32
    a.sl[5] = {2, 7, 0, nullptr, nullptr, S1,      nullptr};   // mvo fp32
    stage2_kernel<<<dim3(DD / 128, MT / 128, 6), 256, 0, stream>>>(Gb512, W2catT, a);

    // --- v-derived operands ---
    vdt_kernel<<<dim3(TT / 32, DD / 32, BB), 256, 0, stream>>>(S0v, d2, VDT);
    a2tv_kernel<<<dim3(DD / 64, 8, BB), 256, 0, stream>>>(S0v, A2T, A2tV);

    // --- C1 = kb^T @ B1 (and scale path), then zB into aug cols ---
    c1_kernel<<<dim3(DD / 64, TT / 256, BB), 256, 0, stream>>>(KBplain, B1T, C1);
    c1_kernel<<<dim3(DD / 64, TT / 256, BB), 256, 0, stream>>>(KSBplain, B1sT, C1s);
    c1conv_kernel<<<(BB * DD * RS) / 256, 256, 0, stream>>>(C1, C1s, C1b, C1sb);
    zb_kernel<<<MT, 256, 0, stream>>>(QGaug, C1b);
    zb_kernel<<<MT, 256, 0, stream>>>(QSGaug, C1sb);

    // --- hm/hs = aug @ aug^T (one launch, 4 z) ---
    hmhs_kernel<<<dim3(TT / 128, TT / 128, 4), 256, 0, stream>>>(
        QGaug, QSGaug, KBaug, KSBaug, hm, hs);

    // --- fuse: norm + HyperGLU -> h, hB ---
    fuse_h3_kernel<<<dim3(TT, BB), 256, 0, stream>>>(hm, hs, B2T, h, hB);

    // --- context + rank16 + mvo + bf16 (fused epilogue) -> cm ---
    ctx_kernel<<<dim3(DD / 128, TT / 128, BB), 256, 0, stream>>>(
        h, VDT, S1, hB, A2tV, cm);

    // --- out = cm @ Wo^T ---
    gemm_nt<0><<<dim3(DD / 128, MT / 128, 1), 256, 0, stream>>>(
        cm, Wob, out, DD, DD, DD, DD, 0, 0, 0);
}

// Round 5
// 400.686 us; speedup vs baseline: 11.2284x; 1.0152x over previous
//
#include <hip/hip_runtime.h>
#include <math.h>

#define BB 2
#define TT 2048
#define DD 1024
#define RS 16
#define MT (BB*TT)      // 4096 flattened rows
#define GLD 640         // stage-1 concat output width (611 used, padded)
#define KAUG 1056       // 1024 + 16 (zB/A1) + 16 zero pad; multiple of 32

typedef __attribute__((ext_vector_type(8))) short s16x8;
typedef __attribute__((ext_vector_type(4))) float f32x4;

__device__ __forceinline__ short f2bf(float f) {
    union { float f; unsigned u; } v; v.f = f;
    unsigned r = (v.u + 0x7fffu + ((v.u >> 16) & 1u)) >> 16;
    return (short)r;
}
__device__ __forceinline__ float bf2f(short s) {
    union { unsigned u; float f; } v; v.u = ((unsigned)(unsigned short)s) << 16;
    return v.f;
}

__device__ __forceinline__ void gload16(const void* g, void* l) {
    __builtin_amdgcn_global_load_lds((const __attribute__((address_space(1))) void*)g,
                                     (__attribute__((address_space(3))) void*)l, 16, 0, 0);
}

// XCD-aware block swizzle (all grids are multiples of 8 -> bijective).
__device__ __forceinline__ void xcd_swz(int& bx, int& by, int& bz)
{
    const int gx = gridDim.x, gy = gridDim.y;
    const int n = gx * gy * (int)gridDim.z;
    int flat = (bz * gy + by) * gx + bx;
    const int cpx = n >> 3;
    flat = (flat & 7) * cpx + (flat >> 3);
    bx = flat % gx; by = (flat / gx) % gy; bz = flat / (gx * gy);
}

// ---------------------------------------------------------------------------
// Shared 128x128 NT tile core: acc = A[bi:bi+128, :K] @ Bt[bj:bj+128, :K]^T
// 4 waves (2x2), 16x16x32 bf16 MFMA, BK=32, global_load_lds staging.
// Granule XOR-swizzle (verified r4: bank conflicts 4.33M -> 0).
// ---------------------------------------------------------------------------
__device__ __forceinline__ void gemm_core128(const short* __restrict__ A,
                                             const short* __restrict__ Bt,
                                             int K, int lda, int ldb,
                                             int bi, int bj, short* smem,
                                             f32x4 (&acc)[4][4])
{
    const int tid = threadIdx.x;
    const int wv = tid >> 6, lane = tid & 63;
    const int wr = (wv >> 1) * 64, wc = (wv & 1) * 64;
    short* Asm = smem;
    short* Bsm = smem + 4096;

#pragma unroll
    for (int m = 0; m < 4; ++m)
#pragma unroll
        for (int n = 0; n < 4; ++n) acc[m][n] = (f32x4){0.f, 0.f, 0.f, 0.f};

    const int srow = wv * 16 + (lane >> 2);                // staging row (+ p*64)
    const int sg   = ((lane & 3) ^ ((srow >> 1) & 3)) * 8; // swizzled src granule
    const int frow = lane & 15;
    const int gidx = lane >> 4;
    const int koff = (gidx ^ ((frow >> 1) & 3)) * 8;       // swizzled read offset

    for (int k0 = 0; k0 < K; k0 += 32) {
#pragma unroll
        for (int p = 0; p < 2; ++p) {
            gload16(A  + (long)(bi + p*64 + srow) * lda + k0 + sg, Asm + p*2048 + wv*512);
            gload16(Bt + (long)(bj + p*64 + srow) * ldb + k0 + sg, Bsm + p*2048 + wv*512);
        }
        __syncthreads();
        s16x8 af[4], bfr[4];
#pragma unroll
        for (int m = 0; m < 4; ++m)
            af[m] = *(const s16x8*)&Asm[(wr + m*16 + frow) * 32 + koff];
#pragma unroll
        for (int n = 0; n < 4; ++n)
            bfr[n] = *(const s16x8*)&Bsm[(wc + n*16 + frow) * 32 + koff];
#pragma unroll
        for (int m = 0; m < 4; ++m)
#pragma unroll
            for (int n = 0; n < 4; ++n)
                acc[m][n] = __builtin_amdgcn_mfma_f32_16x16x32_bf16(af[m], bfr[n], acc[m][n], 0, 0, 0);
        __syncthreads();
    }
}

// Generic batched NT GEMM; STORE 0 = fp32 out, 1 = bf16 out.
template<int STORE>
__global__ __launch_bounds__(256)
void gemm_nt(const short* __restrict__ A, const short* __restrict__ Bt,
             void* __restrict__ Cv, int K, int lda, int ldb, int ldc,
             long sA, long sB, long sC)
{
    int bx = blockIdx.x, by = blockIdx.y, bz = blockIdx.z;
    xcd_swz(bx, by, bz);
    const short* Ab = A  + (long)bz * sA;
    const short* Bb = Bt + (long)bz * sB;
    const int bi = by * 128, bj = bx * 128;
    __shared__ __align__(16) short smem[8192];
    f32x4 acc[4][4];
    gemm_core128(Ab, Bb, K, lda, ldb, bi, bj, smem, acc);

    const int lane = threadIdx.x & 63, wv = threadIdx.x >> 6;
    const int wr = (wv >> 1) * 64, wc = (wv & 1) * 64;
    const int col0 = lane & 15, row0 = (lane >> 4) * 4;
#pragma unroll
    for (int m = 0; m < 4; ++m)
#pragma unroll
        for (int n = 0; n < 4; ++n)
#pragma unroll
            for (int r = 0; r < 4; ++r) {
                int i = bi + wr + m*16 + row0 + r;
                int j = bj + wc + n*16 + col0;
                if (STORE == 0)
                    ((float*)Cv + (long)bz * sC)[(long)i * ldc + j] = acc[m][n][r];
                else
                    ((short*)Cv + (long)bz * sC)[(long)i * ldc + j] = f2bf(acc[m][n][r]);
            }
}

// ---------------------------------------------------------------------------
// Stage-1: xb @ WcatT^T. Epilogue: cols <512 -> Gb512 bf16 (stage-2 input);
// cols 512..610 scattered directly to SoA generator arrays (G never stored).
// Also zeroes aug pad cols 1040..1055 (at j==512, once per row).
// ---------------------------------------------------------------------------
__global__ __launch_bounds__(256)
void gemm_s1(const short* __restrict__ xb, const short* __restrict__ WcatT,
             short* __restrict__ Gb512,
             float* __restrict__ d1, float* __restrict__ d1s, float* __restrict__ d2,
             float* __restrict__ B1T, float* __restrict__ B1sT, float* __restrict__ A2T,
             short* __restrict__ B2T,
             short* __restrict__ QGaug, short* __restrict__ QSGaug,
             short* __restrict__ KBaug, short* __restrict__ KSBaug)
{
    int bx = blockIdx.x, by = blockIdx.y, bz = blockIdx.z;
    xcd_swz(bx, by, bz);
    const int bi = by * 128, bj = bx * 128;
    __shared__ __align__(16) short smem[8192];
    f32x4 acc[4][4];
    gemm_core128(xb, WcatT, DD, DD, DD, bi, bj, smem, acc);

    const int lane = threadIdx.x & 63, wv = threadIdx.x >> 6;
    const int wr = (wv >> 1) * 64, wc = (wv & 1) * 64;
    const int col0 = lane & 15, row0 = (lane >> 4) * 4;
#pragma unroll
    for (int m = 0; m < 4; ++m)
#pragma unroll
        for (int n = 0; n < 4; ++n)
#pragma unroll
            for (int r = 0; r < 4; ++r) {
                int i = bi + wr + m*16 + row0 + r;
                int j = bj + wc + n*16 + col0;
                float val = acc[m][n][r];
                if (j < 512) {
                    Gb512[(long)i * 512 + j] = f2bf(val);
                } else if (j == 512) {
                    d1[i] = val;
                    for (int q = 0; q < RS; ++q) {
                        QGaug [(long)i * KAUG + 1040 + q] = 0;
                        QSGaug[(long)i * KAUG + 1040 + q] = 0;
                        KBaug [(long)i * KAUG + 1040 + q] = 0;
                        KSBaug[(long)i * KAUG + 1040 + q] = 0;
                    }
                } else if (j < 529) {
                    KBaug[(long)i * KAUG + 1024 + (j - 513)] = f2bf(val);
                } else if (j < 545) {
                    B1T[(long)(j - 529) * MT + i] = val;
                } else if (j == 545) {
                    d1s[i] = val;
                } else if (j < 562) {
                    KSBaug[(long)i * KAUG + 1024 + (j - 546)] = f2bf(val);
                } else if (j < 578) {
                    B1sT[(long)(j - 562) * MT + i] = val;
                } else if (j == 578) {
                    d2[i] = val;
                } else if (j < 595) {
                    A2T[(long)(j - 579) * MT + i] = val;
                } else if (j < 611) {
                    B2T[(long)(j - 595) * MT + i] = f2bf(val);
                }
            }
}

// ---------------------------------------------------------------------------
// hmhs_fused: per block computes BOTH gate and scale GEMM tiles, then
// P = softplus(hs) * relu(hm) in-register (bf16 out, norm deferred), and
// accumulates rowsum += sum_j hm^2 via shuffle-reduce + atomics.
// ---------------------------------------------------------------------------
__global__ __launch_bounds__(256)
void hmhs_kernel(const short* __restrict__ QGaug, const short* __restrict__ QSGaug,
                 const short* __restrict__ KBaug, const short* __restrict__ KSBaug,
                 short* __restrict__ P, float* __restrict__ rowsum)
{
    int bx = blockIdx.x, by = blockIdx.y, bz = blockIdx.z;
    xcd_swz(bx, by, bz);
    const int b = bz;
    const int bi = by * 128, bj = bx * 128;
    __shared__ __align__(16) short smem[8192];
    f32x4 acc[4][4], acc2[4][4];
    gemm_core128(QGaug  + (long)b * TT * KAUG, KBaug  + (long)b * TT * KAUG,
                 KAUG, KAUG, KAUG, bi, bj, smem, acc);
    gemm_core128(QSGaug + (long)b * TT * KAUG, KSBaug + (long)b * TT * KAUG,
                 KAUG, KAUG, KAUG, bi, bj, smem, acc2);

    const int lane = threadIdx.x & 63, wv = threadIdx.x >> 6;
    const int wr = (wv >> 1) * 64, wc = (wv & 1) * 64;
    const int col0 = lane & 15, row0 = (lane >> 4) * 4;
    short* Pb = P + (long)b * TT * TT;

    float ss[4][4];
#pragma unroll
    for (int m = 0; m < 4; ++m)
#pragma unroll
        for (int r = 0; r < 4; ++r) ss[m][r] = 0.f;

#pragma unroll
    for (int m = 0; m < 4; ++m)
#pragma unroll
        for (int n = 0; n < 4; ++n)
#pragma unroll
            for (int r = 0; r < 4; ++r) {
                int i = bi + wr + m*16 + row0 + r;
                int j = bj + wc + n*16 + col0;
                float hmv = acc[m][n][r];
                float sv  = acc2[m][n][r];
                float sp  = fmaxf(sv, 0.f) + log1pf(expf(-fabsf(sv)));
                Pb[(long)i * TT + j] = f2bf(sp * fmaxf(hmv, 0.f));
                ss[m][r] = fmaf(hmv, hmv, ss[m][r]);
            }

    // reduce over the 16 col0 lanes (bits 0..3 of lane), then one atomic/row
#pragma unroll
    for (int m = 0; m < 4; ++m)
#pragma unroll
        for (int r = 0; r < 4; ++r) {
            float v = ss[m][r];
            v += __shfl_xor(v, 1, 64);
            v += __shfl_xor(v, 2, 64);
            v += __shfl_xor(v, 4, 64);
            v += __shfl_xor(v, 8, 64);
            if (col0 == 0)
                atomicAdd(&rowsum[(long)b * TT + bi + wr + m*16 + row0 + r], v);
        }
}

// ---------------------------------------------------------------------------
// finish: hB[i][r] = inv[i] * sum_j P[i][j] * B2T[r][j]
// ---------------------------------------------------------------------------
__global__ __launch_bounds__(256)
void finish_kernel(const short* __restrict__ P, const short* __restrict__ B2T,
                   const float* __restrict__ rowsum, float* __restrict__ hB)
{
    const int i = blockIdx.x, b = blockIdx.y, tid = threadIdx.x;
    const long gi = (long)b * TT + i;
    const float inv = 1.f / (sqrtf(rowsum[gi]) + 1e-8f);
    const short* Pr = P + ((long)b * TT + i) * TT;
    const long tb = (long)b * TT;
    const int j0 = tid * 8;

    float hb[RS];
#pragma unroll
    for (int r = 0; r < RS; ++r) hb[r] = 0.f;

    s16x8 pv = *(const s16x8*)&Pr[j0];
    float pf[8];
#pragma unroll
    for (int q = 0; q < 8; ++q) pf[q] = bf2f(pv[q]);
#pragma unroll
    for (int r = 0; r < RS; ++r) {
        s16x8 bv = *(const s16x8*)&B2T[(long)r * MT + tb + j0];
#pragma unroll
        for (int q = 0; q < 8; ++q) hb[r] = fmaf(pf[q], bf2f(bv[q]), hb[r]);
    }
#pragma unroll
    for (int r = 0; r < RS; ++r)
#pragma unroll
        for (int off = 32; off; off >>= 1) hb[r] += __shfl_down(hb[r], off, 64);
    __shared__ float red[4][RS];
    if ((tid & 63) == 0)
#pragma unroll
        for (int r = 0; r < RS; ++r) red[tid >> 6][r] = hb[r];
    __syncthreads();
    if (tid < RS)
        hB[gi * RS + tid] = (red[0][tid] + red[1][tid] + red[2][tid] + red[3][tid]) * inv;
}

// ---------------------------------------------------------------------------
// Stage-2 multi-slice GEMM (K=64 per pass).
// mode 0 (GATE): two passes (sa,sb); out bf16(acc*acc2) at ldc KAUG.
// mode 1 (DUAL): outS2 plain bf16 ldc DD; outS bf16(acc*rs[i]) ldc KAUG.
// mode 2 (F32):  outF fp32 ldc DD.
// ---------------------------------------------------------------------------
struct S2S { int mode, sa, sb; short* outS; short* outS2; float* outF; const float* rs; };
struct S2A { S2S sl[6]; };

__global__ __launch_bounds__(256)
void stage2_kernel(const short* __restrict__ Gb, const short* __restrict__ W2,
                   S2A args)
{
    int bx = blockIdx.x, by = blockIdx.y, bz = blockIdx.z;
    xcd_swz(bx, by, bz);
    const S2S sl = args.sl[bz];
    const int bi = by * 128, bj = bx * 128;
    __shared__ __align__(16) short smem[8192];
    f32x4 acc[4][4];
    gemm_core128(Gb + sl.sa * 64, W2 + (long)sl.sa * DD * 64, 64, 512, 64, bi, bj, smem, acc);
    f32x4 acc2[4][4];
    if (sl.mode == 0)
        gemm_core128(Gb + sl.sb * 64, W2 + (long)sl.sb * DD * 64, 64, 512, 64, bi, bj, smem, acc2);

    const int lane = threadIdx.x & 63, wv = threadIdx.x >> 6;
    const int wr = (wv >> 1) * 64, wc = (wv & 1) * 64;
    const int col0 = lane & 15, row0 = (lane >> 4) * 4;
#pragma unroll
    for (int m = 0; m < 4; ++m)
#pragma unroll
        for (int n = 0; n < 4; ++n)
#pragma unroll
            for (int r = 0; r < 4; ++r) {
                int i = bi + wr + m*16 + row0 + r;
                int j = bj + wc + n*16 + col0;
                float val = acc[m][n][r];
                if (sl.mode == 0) {
                    sl.outS[(long)i * KAUG + j] = f2bf(val * acc2[m][n][r]);
                } else if (sl.mode == 1) {
                    sl.outS2[(long)i * DD + j] = f2bf(val);
                    sl.outS[(long)i * KAUG + j] = f2bf(val * sl.rs[i]);
                } else {
                    sl.outF[(long)i * DD + j] = val;
                }
            }
}

// ---------------------------------------------------------------------------
// Context GEMM, fused epilogue: cm = bf16((P@VDT^T * inv[i] + hB@A2tV) * mvo)
// (hB already carries inv; see finish_kernel.)
// ---------------------------------------------------------------------------
__global__ __launch_bounds__(256)
void ctx_kernel(const short* __restrict__ P, const short* __restrict__ VDT,
                const float* __restrict__ mvo, const float* __restrict__ hB,
                const float* __restrict__ A2tV, const float* __restrict__ rowsum,
                short* __restrict__ cm)
{
    int bx = blockIdx.x, by = blockIdx.y, bz = blockIdx.z;
    xcd_swz(bx, by, bz);
    const int b = bz;
    const int bi = by * 128, bj = bx * 128;
    __shared__ __align__(16) short smem[8192];
    f32x4 acc[4][4];
    gemm_core128(P + (long)b * TT * TT, VDT + (long)b * DD * TT, TT, TT, TT, bi, bj, smem, acc);

    const int lane = threadIdx.x & 63, wv = threadIdx.x >> 6;
    const int wr = (wv >> 1) * 64, wc = (wv & 1) * 64;
    const int col0 = lane & 15, row0 = (lane >> 4) * 4;
    const float* a2 = A2tV + (long)b * RS * DD;

    // apply per-row inv (deferred L2 norm)
#pragma unroll
    for (int m = 0; m < 4; ++m)
#pragma unroll
        for (int r = 0; r < 4; ++r) {
            long gi = (long)b * TT + bi + wr + m*16 + row0 + r;
            float iv = 1.f / (sqrtf(rowsum[gi]) + 1e-8f);
#pragma unroll
            for (int n = 0; n < 4; ++n) acc[m][n][r] *= iv;
        }

    // rank-16 correction
#pragma unroll
    for (int r16 = 0; r16 < RS; ++r16) {
        float a2v[4];
#pragma unroll
        for (int n = 0; n < 4; ++n)
            a2v[n] = a2[(long)r16 * DD + bj + wc + n*16 + col0];
#pragma unroll
        for (int m = 0; m < 4; ++m)
#pragma unroll
            for (int r = 0; r < 4; ++r) {
                long gi = (long)b * TT + bi + wr + m*16 + row0 + r;
                float hb = hB[gi * RS + r16];
#pragma unroll
                for (int n = 0; n < 4; ++n)
                    acc[m][n][r] = fmaf(hb, a2v[n], acc[m][n][r]);
            }
    }
#pragma unroll
    for (int m = 0; m < 4; ++m)
#pragma unroll
        for (int n = 0; n < 4; ++n)
#pragma unroll
            for (int r = 0; r < 4; ++r) {
                long gi = (long)b * TT + bi + wr + m*16 + row0 + r;
                int j = bj + wc + n*16 + col0;
                cm[gi * DD + j] = f2bf(acc[m][n][r] * mvo[gi * DD + j]);
            }
}

// ---------------------------------------------------------------------------
// Weight prep
// ---------------------------------------------------------------------------
struct ConcatArgs { const float* p[17]; int col0[17]; int wid[17]; };

__global__ __launch_bounds__(256)
void concat_w1_kernel(ConcatArgs a, short* __restrict__ WcatT,
                      float* __restrict__ zp, int zn)
{
    const int q = blockIdx.x * 256 + threadIdx.x;
    if (q < zn) zp[q] = 0.f;
    const int n = blockIdx.x;
    int s = -1, c = 0;
    for (int i = 0; i < 17; ++i)
        if (n >= a.col0[i] && n < a.col0[i] + a.wid[i]) { s = i; c = n - a.col0[i]; }
    for (int k = threadIdx.x; k < DD; k += 256)
        WcatT[(long)n * DD + k] = (s < 0) ? (short)0 : f2bf(a.p[s][(long)k * a.wid[s] + c]);
}

struct Ptrs8 { const float* p[8]; };

__global__ __launch_bounds__(256)
void concat_w2_kernel(Ptrs8 a, short* __restrict__ W2catT)
{
    const int s = blockIdx.y, n0 = blockIdx.x * 64;
    const int tx = threadIdx.x & 63, ty = threadIdx.x >> 6;
    __shared__ float t[64][65];
    const float* W2 = a.p[s];
    for (int kk = ty; kk < 64; kk += 4) t[kk][tx] = W2[(long)kk * DD + n0 + tx];
    __syncthreads();
    for (int n = ty; n < 64; n += 4)
        W2catT[((long)s * DD + n0 + n) * 64 + tx] = f2bf(t[tx][n]);
}

__global__ __launch_bounds__(256)
void f2bf_vec_kernel(const float* __restrict__ in, short* __restrict__ o, long n4)
{
    long i = (long)blockIdx.x * 256 + threadIdx.x;
    if (i < n4) {
        float4 v = ((const float4*)in)[i];
        short4 r; r.x = f2bf(v.x); r.y = f2bf(v.y); r.z = f2bf(v.z); r.w = f2bf(v.w);
        ((short4*)o)[i] = r;
    }
}

// ---------------------------------------------------------------------------
// C1[b][d][r] = sum_t kb[b][t][d] * B1T[r][b*TT+t]  (path via blockIdx.z)
// ---------------------------------------------------------------------------
__global__ __launch_bounds__(256)
void c1_kernel(const short* __restrict__ kb0, const float* __restrict__ BT0,
               float* __restrict__ C10)
{
    const int d0 = blockIdx.x * 64, t0 = blockIdx.y * 256;
    const int b = blockIdx.z & 1, path = blockIdx.z >> 1;
    const short* kb = kb0 + (size_t)path * MT * DD;
    const float* BT = BT0 + (size_t)path * RS * MT;
    float* C1 = C10 + (size_t)path * BB * DD * RS;
    const int dl = threadIdx.x & 63, tg = threadIdx.x >> 6;
    float acc[RS];
#pragma unroll
    for (int r = 0; r < RS; ++r) acc[r] = 0.f;
    for (int tt = 0; tt < 64; ++tt) {
        int t = t0 + tg * 64 + tt;
        float kv = bf2f(kb[((long)b * TT + t) * DD + d0 + dl]);
#pragma unroll
        for (int r = 0; r < RS; ++r)
            acc[r] = fmaf(kv, BT[(long)r * MT + b * TT + t], acc[r]);
    }
    __shared__ float red[4][RS][64];
#pragma unroll
    for (int r = 0; r < RS; ++r) red[tg][r][dl] = acc[r];
    __syncthreads();
    for (int q = threadIdx.x; q < RS * 64; q += 256) {
        int r = q >> 6, d = q & 63;
        float s = red[0][r][d] + red[1][r][d] + red[2][r][d] + red[3][r][d];
        atomicAdd(&C1[((long)b * DD + d0 + d) * RS + r], s);
    }
}

// zB[i][:] = qg[i][:1024] @ C1[b] (fp32 C1) -> aug cols 1024..1039
__global__ __launch_bounds__(256)
void zb_kernel(short* __restrict__ aug0, const float* __restrict__ C10)
{
    const int gi = blockIdx.x, path = blockIdx.y, b = gi >> 11, tid = threadIdx.x;
    short* aug = aug0 + (size_t)path * MT * KAUG;
    const float* c1 = C10 + (size_t)path * BB * DD * RS + (long)b * DD * RS;
    const short* qrow = aug + (long)gi * KAUG;
    float acc[RS];
#pragma unroll
    for (int r = 0; r < RS; ++r) acc[r] = 0.f;
#pragma unroll
    for (int c = 0; c < 4; ++c) {
        int d = tid + 256 * c;
        float q = bf2f(qrow[d]);
        const float* cr = c1 + (long)d * RS;
#pragma unroll
        for (int r = 0; r < RS; ++r) acc[r] = fmaf(q, cr[r], acc[r]);
    }
#pragma unroll
    for (int r = 0; r < RS; ++r)
#pragma unroll
        for (int off = 32; off; off >>= 1) acc[r] += __shfl_down(acc[r], off, 64);
    __shared__ float red[4][RS];
    if ((tid & 63) == 0)
#pragma unroll
        for (int r = 0; r < RS; ++r) red[tid >> 6][r] = acc[r];
    __syncthreads();
    if (tid < RS)
        aug[(long)gi * KAUG + 1024 + tid] =
            f2bf(red[0][tid] + red[1][tid] + red[2][tid] + red[3][tid]);
}

// ---------------------------------------------------------------------------
// vdT[b][d][t] = bf16(v[b][t][d] * d2[b*TT+t])
// ---------------------------------------------------------------------------
__global__ __launch_bounds__(256)
void vdt_kernel(const float* __restrict__ v, const float* __restrict__ d2,
                short* __restrict__ o)
{
    const int t0 = blockIdx.x * 32, d0 = blockIdx.y * 32, b = blockIdx.z;
    const int tx = threadIdx.x & 31, ty = threadIdx.x >> 5;
    __shared__ float tile[32][33];
    for (int s = 0; s < 32; s += 8) {
        int t = t0 + ty + s;
        tile[ty + s][tx] = v[((long)b * TT + t) * DD + d0 + tx] * d2[(long)b * TT + t];
    }
    __syncthreads();
    for (int s = 0; s < 32; s += 8) {
        int d = d0 + ty + s;
        o[((long)b * DD + d) * TT + t0 + tx] = f2bf(tile[tx][ty + s]);
    }
}

// A2tV[b][r][d] = sum_t A2T[r][b*TT+t] * v[b][t][d]
__global__ __launch_bounds__(256)
void a2tv_kernel(const float* __restrict__ v, const float* __restrict__ A2T,
                 float* __restrict__ o)
{
    const int d0 = blockIdx.x * 64, ks = blockIdx.y, b = blockIdx.z;
    const int dl = threadIdx.x & 63, tg = threadIdx.x >> 6;
    float acc[RS];
#pragma unroll
    for (int r = 0; r < RS; ++r) acc[r] = 0.f;
    for (int tt = 0; tt < 64; ++tt) {
        int t = ks * 256 + tg * 64 + tt;
        float vv = v[((long)b * TT + t) * DD + d0 + dl];
#pragma unroll
        for (int r = 0; r < RS; ++r)
            acc[r] = fmaf(A2T[(long)r * MT + b * TT + t], vv, acc[r]);
    }
    __shared__ float red[4][RS][64];
#pragma unroll
    for (int r = 0; r < RS; ++r) red[tg][r][dl] = acc[r];
    __syncthreads();
    for (int q = threadIdx.x; q < RS * 64; q += 256) {
        int r = q >> 6, d = q & 63;
        float s = red[0][r][d] + red[1][r][d] + red[2][r][d] + red[3][r][d];
        atomicAdd(&o[((long)b * RS + r) * DD + d0 + d], s);
    }
}

// ---------------------------------------------------------------------------
extern "C" void kernel_launch(void* const* d_in, const int* in_sizes, int n_in,
                              void* d_out, int out_size, void* d_ws, size_t ws_size,
                              hipStream_t stream)
{
    (void)in_sizes; (void)n_in; (void)out_size; (void)ws_size;
    const float* x = (const float*)d_in[0];
    const float* W[27];
    for (int i = 1; i < 27; ++i) W[i] = (const float*)d_in[i];
    float* out = (float*)d_out;

    char* ws = (char*)d_ws;
    size_t off = 0;
    auto alloc = [&](size_t bytes) -> void* {
        void* p = ws + off; off += (bytes + 255) & ~(size_t)255; return p;
    };
    short* xb     = (short*)alloc((size_t)MT * DD * 2);          // -> VDT
    short* WcatT  = (short*)alloc((size_t)GLD * DD * 2);
    short* W2catT = (short*)alloc((size_t)8 * DD * 64 * 2);
    short* Gb512  = (short*)alloc((size_t)MT * 512 * 2);
    short* Wob    = (short*)alloc((size_t)DD * DD * 2);
    float* S1     = (float*)alloc((size_t)MT * DD * 4);          // mvo fp32
    float* S0v    = (float*)alloc((size_t)MT * DD * 4);          // v fp32
    short* QGaug  = (short*)alloc((size_t)MT * KAUG * 2);        // | contiguous
    short* QSGaug = (short*)alloc((size_t)MT * KAUG * 2);        // |
    short* KBaug  = (short*)alloc((size_t)MT * KAUG * 2);
    short* KSBaug = (short*)alloc((size_t)MT * KAUG * 2);
    short* KBplain  = (short*)alloc((size_t)MT * DD * 2);        // | contig, -> cm
    short* KSBplain = (short*)alloc((size_t)MT * DD * 2);        // |
    short* P      = (short*)alloc((size_t)BB * TT * TT * 2);
    float* d1   = (float*)alloc((size_t)MT * 4);
    float* d1s  = (float*)alloc((size_t)MT * 4);
    float* d2   = (float*)alloc((size_t)MT * 4);
    float* B1T  = (float*)alloc((size_t)RS * MT * 4);            // | contiguous
    float* B1sT = (float*)alloc((size_t)RS * MT * 4);            // |
    float* A2T  = (float*)alloc((size_t)RS * MT * 4);
    short* B2T  = (short*)alloc((size_t)RS * MT * 2);
    float* C1   = (float*)alloc((size_t)BB * DD * RS * 4);       // | contiguous
    float* C1s  = (float*)alloc((size_t)BB * DD * RS * 4);       // | zero block
    float* A2tV = (float*)alloc((size_t)BB * RS * DD * 4);       // |
    float* rowsum = (float*)alloc((size_t)MT * 4);               // | (zeroed too)
    float* hB   = (float*)alloc((size_t)MT * RS * 4);

    short* VDT = xb;        // xb dead after stage-1
    short* cm  = KBplain;   // KBplain dead after c1

    const long n4 = (long)MT * DD / 4;
    const int ZN = 3 * BB * DD * RS + MT;   // C1+C1s+A2tV+rowsum floats

    // --- input/weight conversion (+ zero accumulators) ---
    f2bf_vec_kernel<<<n4 / 256, 256, 0, stream>>>(x, xb, n4);
    ConcatArgs ca;
    {
        const int w1idx[8] = {1, 3, 5, 7, 9, 11, 13, 15};
        for (int s = 0; s < 8; ++s) { ca.p[s] = W[w1idx[s]]; ca.col0[s] = s * 64; ca.wid[s] = 64; }
        const int didx[9] = {18, 19, 20, 21, 22, 23, 24, 25, 26};
        const int dcol[9] = {512, 513, 529, 545, 546, 562, 578, 579, 595};
        const int dwid[9] = {1, 16, 16, 1, 16, 16, 1, 16, 16};
        for (int s = 0; s < 9; ++s) { ca.p[8 + s] = W[didx[s]]; ca.col0[8 + s] = dcol[s]; ca.wid[8 + s] = dwid[s]; }
    }
    concat_w1_kernel<<<GLD, 256, 0, stream>>>(ca, WcatT, C1, ZN);
    Ptrs8 p8;
    {
        const int w2idx[8] = {2, 4, 6, 8, 10, 12, 14, 16};
        for (int s = 0; s < 8; ++s) p8.p[s] = W[w2idx[s]];
    }
    concat_w2_kernel<<<dim3(DD / 64, 8), 256, 0, stream>>>(p8, W2catT);
    f2bf_vec_kernel<<<((long)DD * DD / 4) / 256, 256, 0, stream>>>(W[17], Wob, (long)DD * DD / 4);

    // --- stage-1 (SoA scatter epilogue; G never materialized) ---
    gemm_s1<<<dim3(GLD / 128, MT / 128, 1), 256, 0, stream>>>(
        xb, WcatT, Gb512, d1, d1s, d2, B1T, B1sT, A2T, B2T,
        QGaug, QSGaug, KBaug, KSBaug);

    // --- stage-2: one launch, 6 slices (gate products fused) ---
    S2A a;
    a.sl[0] = {0, 0, 1, QGaug,  nullptr,  nullptr, nullptr};   // q*mg
    a.sl[1] = {0, 3, 4, QSGaug, nullptr,  nullptr, nullptr};   // qs*mgs
    a.sl[2] = {1, 2, 0, KBaug,  KBplain,  nullptr, d1};        // k dual
    a.sl[3] = {1, 5, 0, KSBaug, KSBplain, nullptr, d1s};       // ks dual
    a.sl[4] = {2, 6, 0, nullptr, nullptr, S0v,     nullptr};   // v fp32
    a.sl[5] = {2, 7, 0, nullptr, nullptr, S1,      nullptr};   // mvo fp32
    stage2_kernel<<<dim3(DD / 128, MT / 128, 6), 256, 0, stream>>>(Gb512, W2catT, a);

    // --- v-derived operands ---
    vdt_kernel<<<dim3(TT / 32, DD / 32, BB), 256, 0, stream>>>(S0v, d2, VDT);
    a2tv_kernel<<<dim3(DD / 64, 8, BB), 256, 0, stream>>>(S0v, A2T, A2tV);

    // --- C1 (both paths, one launch), then zB into aug cols (one launch) ---
    c1_kernel<<<dim3(DD / 64, TT / 256, 2 * BB), 256, 0, stream>>>(KBplain, B1T, C1);
    zb_kernel<<<dim3(MT, 2), 256, 0, stream>>>(QGaug, C1);

    // --- fused hm/hs GEMMs + HyperGLU -> P, rowsum ---
    hmhs_kernel<<<dim3(TT / 128, TT / 128, BB), 256, 0, stream>>>(
        QGaug, QSGaug, KBaug, KSBaug, P, rowsum);

    // --- finish: hB (inv folded) ---
    finish_kernel<<<dim3(TT, BB), 256, 0, stream>>>(P, B2T, rowsum, hB);

    // --- context + inv + rank16 + mvo -> cm ---
    ctx_kernel<<<dim3(DD / 128, TT / 128, BB), 256, 0, stream>>>(
        P, VDT, S1, hB, A2tV, rowsum, cm);

    // --- out = cm @ Wo^T ---
    gemm_nt<0><<<dim3(DD / 128, MT / 128, 1), 256, 0, stream>>>(
        cm, Wob, out, DD, DD, DD, DD, 0, 0, 0);
}